// Round 7
// baseline (325.936 us; speedup 1.0000x reference)
//
#include <hip/hip_runtime.h>
#include <stdint.h>

#define BB 4
#define CC 256
#define HH 64
#define WWD 64
#define NN 4096
#define LOG2E 1.4426950408889634f

typedef __attribute__((ext_vector_type(8))) short short8;
typedef __attribute__((ext_vector_type(4))) float f32x4;
typedef __attribute__((ext_vector_type(16))) float f32x16;
typedef __attribute__((ext_vector_type(4))) unsigned short us4;
typedef unsigned long long ull;

__device__ __forceinline__ unsigned short f2bf(float f) {
  unsigned int u = __float_as_uint(f);
  u += 0x7fffu + ((u >> 16) & 1u);          // RNE
  return (unsigned short)(u >> 16);
}
__device__ __forceinline__ float bf2f(unsigned short h) {
  return __uint_as_float(((unsigned int)h) << 16);
}
__device__ __forceinline__ short8 ld8(const unsigned short* p) {
  return *reinterpret_cast<const short8*>(p);
}
__device__ __forceinline__ unsigned char f2fp8(float v) {   // OCP e4m3 via HW cvt (RNE)
  return (unsigned char)__builtin_amdgcn_cvt_pk_fp8_f32(v, v, 0, false);
}
__device__ __forceinline__ int rowmap(int reg, int h) {     // 32x32 C/D row map
  return (reg & 3) + 8 * (reg >> 2) + 4 * h;
}

// ---------------- k_pre: z<8 -> transpose (+psum partials, +dwconv for x_self);
//                  z==8 -> weight fp32->bf16 cast slice
__global__ __launch_bounds__(256, 2) void k_pre(
    const float* __restrict__ xs, const float* __restrict__ xo,
    const float* __restrict__ dww, const float* __restrict__ dwb,
    const float* __restrict__ bng, const float* __restrict__ bnb,
    const float* __restrict__ bnm, const float* __restrict__ bnv,
    const float* __restrict__ qw, const float* __restrict__ kvw,
    const float* __restrict__ ow, unsigned short* __restrict__ XtS,
    unsigned short* __restrict__ XtO, unsigned short* __restrict__ localT,
    float* __restrict__ psumA, unsigned short* __restrict__ Wb) {
  __shared__ float rb3[3][64][67];
  __shared__ unsigned short sb[64][67];
  int tid = threadIdx.x;
  if (blockIdx.z == 8) {                    // weight cast
    int i = (blockIdx.x * 64 + blockIdx.y) * 1024 + tid * 4;
    const float* src;
    if (i < 65536) src = qw + i;
    else if (i < 196608) src = kvw + (i - 65536);
    else src = ow + (i - 196608);
    f32x4 v = *reinterpret_cast<const f32x4*>(src);
    us4 r;
#pragma unroll
    for (int j = 0; j < 4; ++j) r[j] = f2bf(v[j]);
    *reinterpret_cast<us4*>(Wb + i) = r;
    return;
  }
  int c0 = blockIdx.x * 64, h = blockIdx.y;
  int b = blockIdx.z >> 1, which = blockIdx.z & 1;
  const float* src = which ? xo : xs;
  int wq = tid >> 6, w = tid & 63;
  int dlo = which ? 1 : 0, dhi = which ? 1 : 2;
  for (int d = dlo; d <= dhi; ++d) {
    int hh = h + d - 1;
    bool ok = (hh >= 0 && hh < HH);
#pragma unroll
    for (int p = 0; p < 4; ++p) {
      int idx = p * 256 + tid;
      int cl = idx >> 4, ws4 = (idx & 15) * 4;
      f32x4 v = {};
      if (ok)
        v = *reinterpret_cast<const f32x4*>(
            &src[(((size_t)(b * CC + c0 + cl)) * HH + hh) * WWD + ws4]);
#pragma unroll
      for (int j = 0; j < 4; ++j) rb3[d][cl][ws4 + 1 + j] = v[j];
    }
    if (tid < 64) { rb3[d][tid][0] = 0.f; rb3[d][tid][65] = 0.f; }
  }
  __syncthreads();
  // transpose-store middle row -> Xt
  unsigned short* dst = which ? XtO : XtS;
  int n0 = h * 64, cb = (tid & 15) * 4;
#pragma unroll
  for (int i = 0; i < 4; ++i) {
    int wl = i * 16 + (tid >> 4);
    us4 r;
#pragma unroll
    for (int j = 0; j < 4; ++j) r[j] = f2bf(rb3[1][cb + j][wl + 1]);
    *reinterpret_cast<us4*>(&dst[((size_t)b * NN + n0 + wl) * CC + c0 + cb]) = r;
  }
  if (which) return;
  if (tid < 64) {                           // channel-sum partial
    float s = 0.f;
    for (int ww = 0; ww < 64; ++ww) s += rb3[1][tid][ww + 1];
    psumA[((size_t)(b * 64 + h)) * CC + c0 + tid] = s;
  }
  // depthwise 3x3 + BN + SiLU
  for (int p = 0; p < 16; ++p) {
    int cl = p * 4 + wq, c = c0 + cl;
    float acc = 0.f;
#pragma unroll
    for (int di = 0; di < 3; ++di)
#pragma unroll
      for (int dj = 0; dj < 3; ++dj)
        acc = fmaf(rb3[di][cl][w + dj], dww[c * 9 + di * 3 + dj], acc);
    float y = acc + dwb[c];
    float sc = bng[c] * rsqrtf(bnv[c] + 1e-5f);
    float v = (y - bnm[c]) * sc + bnb[c];
    sb[cl][w] = f2bf(v / (1.f + __expf(-v)));
  }
  __syncthreads();
#pragma unroll
  for (int i = 0; i < 4; ++i) {
    int wl = i * 16 + (tid >> 4);
    us4 r;
#pragma unroll
    for (int j = 0; j < 4; ++j) r[j] = sb[cb + j][wl];
    *reinterpret_cast<us4*>(&localT[((size_t)b * NN + h * WWD + wl) * CC + c0 + cb]) = r;
  }
}

// --------- fused Q,K,V projections. id 0/1: Q,K -> FRAGMENT-LINEAR fp8 (flash reads
// 512B-coalesced frags from global/L2). id 2: V row-major fp8 [o][n]. id 3: gate.
// Q,K carry sqrt-split softmax scale (0.25 each).
__global__ __launch_bounds__(256, 4) void k_qkv(
    const unsigned short* __restrict__ XtS, const unsigned short* __restrict__ XtO,
    const unsigned short* __restrict__ Wb, const float* __restrict__ qb,
    const float* __restrict__ kvb, const float* __restrict__ psumA,
    const float* __restrict__ g1w, const float* __restrict__ g1b,
    const float* __restrict__ g2w, const float* __restrict__ g2b,
    unsigned char* __restrict__ Qt8, unsigned char* __restrict__ Kt8,
    unsigned char* __restrict__ Vv8, float* __restrict__ gate) {
  __shared__ unsigned short Xs[64][264];   // 33.8 KB; reused as fp8 transpose buffer
  int tid = threadIdx.x;
  int id = blockIdx.y;
  if (id == 3) {                            // gate (SE path), one working block
    if (blockIdx.x != 0 || blockIdx.z != 0) return;
    float* mf = (float*)&Xs[0][0];
    float* hpf = mf + 1024;
    int c = tid;
    for (int b4 = 0; b4 < 4; ++b4) {
      float s = 0.f;
      for (int hh = 0; hh < 64; ++hh) s += psumA[((size_t)(b4 * 64 + hh)) * CC + c];
      mf[b4 * 256 + c] = s * (1.f / 4096.f);
    }
    __syncthreads();
    for (int b4 = 0; b4 < 4; ++b4) {
      int j = tid >> 2, cq = tid & 3;
      float s = 0.f;
      for (int cc = cq * 64; cc < cq * 64 + 64; ++cc)
        s = fmaf(mf[b4 * 256 + cc], g1w[j * CC + cc], s);
      hpf[j * 5 + cq] = s;
      __syncthreads();
      if (tid < 64) {
        float hh = fmaxf(hpf[tid * 5] + hpf[tid * 5 + 1] + hpf[tid * 5 + 2] +
                             hpf[tid * 5 + 3] + g1b[tid], 0.f);
        float t = hh * g2w[tid];
        for (int off = 32; off; off >>= 1) t += __shfl_down(t, off, 64);
        if (tid == 0) gate[b4] = 1.f / (1.f + expf(-(t + g2b[0])));
      }
      __syncthreads();
    }
    return;
  }
  int n0 = blockIdx.x * 64, b = blockIdx.z;
  const unsigned short* Xt = (id == 0) ? XtS : XtO;
  const unsigned short* W = Wb + id * 65536;
  int wave = tid >> 6, lane = tid & 63, l31 = lane & 31, h = lane >> 5;
#pragma unroll
  for (int p = 0; p < 8; ++p) {
    int r = p * 8 + (tid >> 5), c = (tid & 31) * 8;
    *reinterpret_cast<uint4*>(&Xs[r][c]) =
        *reinterpret_cast<const uint4*>(Xt + ((size_t)b * NN + n0 + r) * CC + c);
  }
  __syncthreads();
  int o0 = wave * 64;
  f32x16 acc[4] = {};
  if (id < 2) {
#pragma unroll
    for (int t = 0; t < 16; ++t) {
      short8 a0 = ld8(&Xs[l31][t * 16 + h * 8]);
      short8 a1 = ld8(&Xs[32 + l31][t * 16 + h * 8]);
      short8 b0 = ld8(W + (size_t)(o0 + l31) * CC + t * 16 + h * 8);
      short8 b1 = ld8(W + (size_t)(o0 + 32 + l31) * CC + t * 16 + h * 8);
      acc[0] = __builtin_amdgcn_mfma_f32_32x32x16_bf16(a0, b0, acc[0], 0, 0, 0);
      acc[1] = __builtin_amdgcn_mfma_f32_32x32x16_bf16(a0, b1, acc[1], 0, 0, 0);
      acc[2] = __builtin_amdgcn_mfma_f32_32x32x16_bf16(a1, b0, acc[2], 0, 0, 0);
      acc[3] = __builtin_amdgcn_mfma_f32_32x32x16_bf16(a1, b1, acc[3], 0, 0, 0);
    }
    const float* bias = id ? kvb : qb;
    unsigned char* Out8 = id ? Kt8 : Qt8;
    __syncthreads();                        // Xs MFMA reads done
    unsigned char (*T8)[264] = reinterpret_cast<unsigned char(*)[264]>(&Xs[0][0]);
#pragma unroll
    for (int nt = 0; nt < 2; ++nt)
#pragma unroll
      for (int ot = 0; ot < 2; ++ot) {
        int o = o0 + ot * 32 + l31;
        float bv = bias[o];
#pragma unroll
        for (int reg = 0; reg < 16; ++reg) {
          int nl = nt * 32 + rowmap(reg, h);
          T8[nl][o] = f2fp8((acc[nt * 2 + ot][reg] + bv) * 0.25f);
        }
      }
    __syncthreads();
    // store FRAGMENT-LINEAR: chunk = ((b*128 + mtile)*16 + kt)*512 + li*8
    // element (n,o): mtile=n>>5, kt=o>>4, li=(n&31)+32*((o>>3)&1), byte=o&7
#pragma unroll
    for (int p = 0; p < 8; ++p) {
      int idx = p * 256 + tid;              // 0..2047 chunks of 8B
      int msel = idx >> 10, rem = idx & 1023;
      int kt = rem >> 6, li = rem & 63;
      int row = (li & 31) + 32 * msel;
      int col = kt * 16 + (li >> 5) * 8;
      ull v = *reinterpret_cast<const ull*>(&T8[row][col]);
      *reinterpret_cast<ull*>(
          Out8 + (((size_t)b * 128 + (n0 >> 5) + msel) * 16 + kt) * 512 + li * 8) = v;
    }
  } else {
    // V[o][n]
#pragma unroll
    for (int t = 0; t < 16; ++t) {
      short8 a0 = ld8(W + (size_t)(o0 + l31) * CC + t * 16 + h * 8);
      short8 a1 = ld8(W + (size_t)(o0 + 32 + l31) * CC + t * 16 + h * 8);
      short8 b0 = ld8(&Xs[l31][t * 16 + h * 8]);
      short8 b1 = ld8(&Xs[32 + l31][t * 16 + h * 8]);
      acc[0] = __builtin_amdgcn_mfma_f32_32x32x16_bf16(a0, b0, acc[0], 0, 0, 0);
      acc[1] = __builtin_amdgcn_mfma_f32_32x32x16_bf16(a0, b1, acc[1], 0, 0, 0);
      acc[2] = __builtin_amdgcn_mfma_f32_32x32x16_bf16(a1, b0, acc[2], 0, 0, 0);
      acc[3] = __builtin_amdgcn_mfma_f32_32x32x16_bf16(a1, b1, acc[3], 0, 0, 0);
    }
    __syncthreads();
    unsigned char (*V8)[72] = reinterpret_cast<unsigned char(*)[72]>(&Xs[0][0]);
#pragma unroll
    for (int ot = 0; ot < 2; ++ot)
#pragma unroll
      for (int nt = 0; nt < 2; ++nt)
#pragma unroll
        for (int reg = 0; reg < 16; ++reg) {
          int o = o0 + ot * 32 + rowmap(reg, h);
          int nl = nt * 32 + l31;
          V8[o][nl] = f2fp8(acc[ot * 2 + nt][reg] + kvb[CC + o]);
        }
    __syncthreads();
#pragma unroll
    for (int p = 0; p < 4; ++p) {
      int idx = p * 256 + tid, o = idx >> 2, mm = (idx & 3) * 16;
      ull a0 = *reinterpret_cast<const ull*>(&V8[o][mm]);
      ull a1 = *reinterpret_cast<const ull*>(&V8[o][mm + 8]);
      uint4 u;
      u.x = (unsigned)a0; u.y = (unsigned)(a0 >> 32);
      u.z = (unsigned)a1; u.w = (unsigned)(a1 >> 32);
      *reinterpret_cast<uint4*>(Vv8 + ((size_t)b * CC + o) * NN + n0 + mm) = u;
    }
  }
}

// ------------- flash attention: Q,K frag-linear from global (L2, XCD-pinned);
// only V + P in LDS (23.8 KB) -> 4 blocks/CU. S-phase touches no LDS, so V-load
// latency hides under the 16 QK MFMAs with no barrier coupling.
__global__ __launch_bounds__(256, 4) void k_flash8(
    const unsigned char* __restrict__ Qt8, const unsigned char* __restrict__ Kt8,
    const unsigned char* __restrict__ Vv8, const unsigned short* __restrict__ localT,
    const float* __restrict__ gate, unsigned short* __restrict__ Opart16,
    float* __restrict__ Lpart, unsigned short* __restrict__ fusedT) {
  __shared__ unsigned char Vs8[256][72];
  __shared__ unsigned char Ps8[64][72];
  __shared__ float lred[2][64];
  __shared__ float ltot[64];
  // XCD swizzle: b = x&3 -> Q+K+V fp8 per b = 3MB, per-XCD-L2-resident
  int b = blockIdx.x & 3, n0 = (blockIdx.x >> 2) * 64;
  int sp = blockIdx.y, nsp = gridDim.y;
  int tid = threadIdx.x, wave = tid >> 6, lane = tid & 63, l31 = lane & 31, h = lane >> 5;
  int rw = wave & 1, cw = wave >> 1;
  const unsigned char* qbase =
      Qt8 + (((size_t)b * 128 + (n0 >> 5) + rw) * 16) * 512 + lane * 8;
  f32x16 O[4] = {};
  float lacc[16] = {};
  int m_lo = (64 * sp) / nsp, m_hi = (64 * (sp + 1)) / nsp;
  for (int mt = m_lo; mt < m_hi; ++mt) {
    int m0 = mt * 64;
    __syncthreads();          // prior iter's Vs/Ps reads complete
    // issue V tile loads (global -> regs); latency overlaps the S-phase below
    uint4 vreg[4];
#pragma unroll
    for (int p = 0; p < 4; ++p) {
      int idx = p * 256 + tid, c = idx >> 2, mm = (idx & 3) * 16;
      vreg[p] = *reinterpret_cast<const uint4*>(Vv8 + ((size_t)b * CC + c) * NN + m0 + mm);
    }
    // S = Q K^T : frags straight from global (coalesced 512B/wave, L2 hits)
    const unsigned char* kb =
        Kt8 + (((size_t)b * 128 + (mt * 2 + cw)) * 16) * 512 + lane * 8;
    f32x16 S = {};
#pragma unroll
    for (int t = 0; t < 16; ++t) {
      long qf = *reinterpret_cast<const long*>(qbase + t * 512);
      long kf = *reinterpret_cast<const long*>(kb + t * 512);
      S = __builtin_amdgcn_mfma_f32_32x32x16_fp8_fp8(qf, kf, S, 0, 0, 0);
    }
    // commit V tile to LDS
#pragma unroll
    for (int p = 0; p < 4; ++p) {
      int idx = p * 256 + tid, c = idx >> 2, mm = (idx & 3) * 16;
      ull lo = ((ull)vreg[p].y << 32) | vreg[p].x;
      ull hi = ((ull)vreg[p].w << 32) | vreg[p].z;
      *reinterpret_cast<ull*>(&Vs8[c][mm]) = lo;
      *reinterpret_cast<ull*>(&Vs8[c][mm + 8]) = hi;
    }
    // P = exp(S) -> fp8; row-sum accumulate
#pragma unroll
    for (int reg = 0; reg < 16; ++reg) {
      float p = __builtin_exp2f(S[reg] * LOG2E);
      lacc[reg] += p;
      Ps8[rw * 32 + rowmap(reg, h)][cw * 32 + l31] = f2fp8(p);
    }
    __syncthreads();
    // O += P V^T : rows rw*32, cols cw*128, k=64
#pragma unroll
    for (int t = 0; t < 4; ++t) {
      long pf = *reinterpret_cast<const long*>(&Ps8[rw * 32 + l31][t * 16 + h * 8]);
#pragma unroll
      for (int ct = 0; ct < 4; ++ct) {
        long vf = *reinterpret_cast<const long*>(&Vs8[cw * 128 + ct * 32 + l31][t * 16 + h * 8]);
        O[ct] = __builtin_amdgcn_mfma_f32_32x32x16_fp8_fp8(pf, vf, O[ct], 0, 0, 0);
      }
    }
  }
#pragma unroll
  for (int reg = 0; reg < 16; ++reg) {
    float v = lacc[reg];
#pragma unroll
    for (int msk = 1; msk < 32; msk <<= 1) v += __shfl_xor(v, msk, 64);
    lacc[reg] = v;
  }
  __syncthreads();
#pragma unroll
  for (int g = 0; g < 16; ++g)
    if (l31 == g) lred[cw][rw * 32 + rowmap(g, h)] = lacc[g];
  __syncthreads();
  size_t obase2 = (size_t)(b * nsp + sp) * NN;
  if (nsp == 1) {
    if (tid < 64) ltot[tid] = lred[0][tid] + lred[1][tid];
    __syncthreads();
    float gv = gate[b];
    float inv[16];
#pragma unroll
    for (int reg = 0; reg < 16; ++reg)
      inv[reg] = gv / ltot[rw * 32 + rowmap(reg, h)];
#pragma unroll
    for (int ct = 0; ct < 4; ++ct)
#pragma unroll
      for (int reg = 0; reg < 16; ++reg) {
        int n = n0 + rw * 32 + rowmap(reg, h);
        int c = cw * 128 + ct * 32 + l31;
        size_t idx = ((size_t)b * NN + n) * CC + c;
        fusedT[idx] = f2bf(bf2f(localT[idx]) + O[ct][reg] * inv[reg]);
      }
  } else {
    if (tid < 64) Lpart[obase2 + n0 + tid] = lred[0][tid] + lred[1][tid];
#pragma unroll
    for (int ct = 0; ct < 4; ++ct)
#pragma unroll
      for (int reg = 0; reg < 16; ++reg) {
        int n = n0 + rw * 32 + rowmap(reg, h);
        int c = cw * 128 + ct * 32 + l31;
        Opart16[(obase2 + n) * CC + c] = f2bf(O[ct][reg]);
      }
  }
}

// --------- out projection with fused split-combine (Opart bf16)
__global__ __launch_bounds__(256, 4) void k_out(
    const unsigned short* __restrict__ W, const float* __restrict__ ob,
    const float* __restrict__ gate, const unsigned short* __restrict__ localT,
    const unsigned short* __restrict__ Opart16, const float* __restrict__ Lpart,
    const unsigned short* __restrict__ fusedT, float* __restrict__ out, int nsp) {
  __shared__ unsigned short Xs[64][264];
  int n0 = blockIdx.x * 64, o0 = blockIdx.y * 128, b = blockIdx.z;
  int tid = threadIdx.x, wave = tid >> 6, lane = tid & 63, l31 = lane & 31, h = lane >> 5;
  if (Opart16) {
    float gv = gate[b];
#pragma unroll
    for (int p = 0; p < 8; ++p) {
      int r = p * 8 + (tid >> 5), cc = (tid & 31) * 8;
      int n = n0 + r;
      float lsum = 0.f;
      for (int sp = 0; sp < nsp; ++sp) lsum += Lpart[(size_t)(b * nsp + sp) * NN + n];
      float g = gv / lsum;
      float ov[8] = {};
      for (int sp = 0; sp < nsp; ++sp) {
        short8 x = ld8(Opart16 + ((size_t)(b * nsp + sp) * NN + n) * CC + cc);
#pragma unroll
        for (int j = 0; j < 8; ++j) ov[j] += bf2f(((unsigned short*)&x)[j]);
      }
      const unsigned short* lp = localT + ((size_t)b * NN + n) * CC + cc;
      short8 lv = ld8(lp);
      us4 r0, r1;
#pragma unroll
      for (int j = 0; j < 4; ++j) {
        r0[j] = f2bf(bf2f(((unsigned short*)&lv)[j]) + ov[j] * g);
        r1[j] = f2bf(bf2f(((unsigned short*)&lv)[j + 4]) + ov[j + 4] * g);
      }
      *reinterpret_cast<us4*>(&Xs[r][cc]) = r0;
      *reinterpret_cast<us4*>(&Xs[r][cc + 4]) = r1;
    }
  } else {
#pragma unroll
    for (int p = 0; p < 8; ++p) {
      int r = p * 8 + (tid >> 5), c = (tid & 31) * 8;
      *reinterpret_cast<uint4*>(&Xs[r][c]) =
          *reinterpret_cast<const uint4*>(fusedT + ((size_t)b * NN + n0 + r) * CC + c);
    }
  }
  int obase = o0 + wave * 32;
  short8 af[16];
#pragma unroll
  for (int t = 0; t < 16; ++t) af[t] = ld8(W + (size_t)(obase + l31) * CC + t * 16 + h * 8);
  __syncthreads();
  f32x16 acc[2] = {};
#pragma unroll
  for (int t = 0; t < 16; ++t) {
    short8 b0 = ld8(&Xs[l31][t * 16 + h * 8]);
    short8 b1 = ld8(&Xs[32 + l31][t * 16 + h * 8]);
    acc[0] = __builtin_amdgcn_mfma_f32_32x32x16_bf16(af[t], b0, acc[0], 0, 0, 0);
    acc[1] = __builtin_amdgcn_mfma_f32_32x32x16_bf16(af[t], b1, acc[1], 0, 0, 0);
  }
#pragma unroll
  for (int nt = 0; nt < 2; ++nt)
#pragma unroll
    for (int reg = 0; reg < 16; ++reg) {
      int o = obase + rowmap(reg, h);
      int n = n0 + nt * 32 + l31;
      out[((size_t)b * CC + o) * NN + n] = acc[nt][reg] + ob[o];
    }
}

// ---------------------------------------------------------------------------- launch
extern "C" void kernel_launch(void* const* d_in, const int* in_sizes, int n_in,
                              void* d_out, int out_size, void* d_ws, size_t ws_size,
                              hipStream_t stream) {
  const float* xs  = (const float*)d_in[0];
  const float* xo  = (const float*)d_in[1];
  const float* qw  = (const float*)d_in[2];
  const float* qb  = (const float*)d_in[3];
  const float* kvw = (const float*)d_in[4];
  const float* kvb = (const float*)d_in[5];
  const float* g1w = (const float*)d_in[6];
  const float* g1b = (const float*)d_in[7];
  const float* g2w = (const float*)d_in[8];
  const float* g2b = (const float*)d_in[9];
  const float* dww = (const float*)d_in[10];
  const float* dwb = (const float*)d_in[11];
  const float* bng = (const float*)d_in[12];
  const float* bnb = (const float*)d_in[13];
  const float* bnm = (const float*)d_in[14];
  const float* bnv = (const float*)d_in[15];
  const float* ow  = (const float*)d_in[16];
  const float* ob  = (const float*)d_in[17];
  float* out = (float*)d_out;
  char* ws = (char*)d_ws;

  const size_t SZ  = (size_t)BB * NN * CC * 2;            // 8 MB bf16 tensor
  const size_t SZ8 = (size_t)BB * NN * CC;                // 4 MB fp8 tensor
  unsigned short* XtS    = (unsigned short*)(ws);
  unsigned short* XtO    = (unsigned short*)(ws + SZ);
  unsigned short* localT = (unsigned short*)(ws + 2 * SZ);
  unsigned char*  Qt8    = (unsigned char*)(ws + 3 * SZ);            // frag-linear
  unsigned char*  Kt8    = (unsigned char*)(ws + 3 * SZ + SZ8);      // frag-linear
  unsigned char*  Vv8    = (unsigned char*)(ws + 3 * SZ + 2 * SZ8);  // row-major [b][o][n]
  unsigned short* Wb     = (unsigned short*)(ws + 3 * SZ + 3 * SZ8); // 512 KB
  float* psumA = (float*)(ws + 3 * SZ + 3 * SZ8 + 524288);           // 256 KB
  float* gate  = (float*)(ws + 3 * SZ + 3 * SZ8 + 524288 + 262144);  // 16 B
  size_t tail  = 3 * SZ + 3 * SZ8 + 524288 + 262144 + 4096;
  float* Lpart = (float*)(ws + tail);                                // 256 KB
  unsigned short* Opart16 = (unsigned short*)(ws + tail + 262144);   // nsp*8 MB
  unsigned short* fusedT = XtS;                                      // dead after k_qkv

  size_t base = tail + 262144;
  int S = 1;
  if (ws_size >= base + 4ull * SZ) S = 4;          // 1024 blocks = 4/CU
  else if (ws_size >= base + 3ull * SZ) S = 3;
  else if (ws_size >= base + 2ull * SZ) S = 2;

  k_pre<<<dim3(4, 64, 9), 256, 0, stream>>>(xs, xo, dww, dwb, bng, bnb, bnm, bnv,
                                            qw, kvw, ow, XtS, XtO, localT, psumA, Wb);
  k_qkv<<<dim3(64, 4, 4), 256, 0, stream>>>(XtS, XtO, Wb, qb, kvb, psumA,
                                            g1w, g1b, g2w, g2b, Qt8, Kt8, Vv8, gate);
  k_flash8<<<dim3(256, S), 256, 0, stream>>>(Qt8, Kt8, Vv8, localT, gate, Opart16,
                                             Lpart, fusedT);
  k_out<<<dim3(64, 2, 4), 256, 0, stream>>>(Wb + 196608, ob, gate, localT,
                                            S > 1 ? Opart16 : nullptr, Lpart, fusedT,
                                            out, S);
}

// Round 8
// 271.691 us; speedup vs baseline: 1.1997x; 1.1997x over previous
//
#include <hip/hip_runtime.h>
#include <stdint.h>

#define BB 4
#define CC 256
#define HH 64
#define WWD 64
#define NN 4096
#define LOG2E 1.4426950408889634f

typedef __attribute__((ext_vector_type(8))) short short8;
typedef __attribute__((ext_vector_type(4))) float f32x4;
typedef __attribute__((ext_vector_type(16))) float f32x16;
typedef __attribute__((ext_vector_type(4))) unsigned short us4;
typedef unsigned long long ull;

__device__ __forceinline__ unsigned short f2bf(float f) {
  unsigned int u = __float_as_uint(f);
  u += 0x7fffu + ((u >> 16) & 1u);          // RNE
  return (unsigned short)(u >> 16);
}
__device__ __forceinline__ float bf2f(unsigned short h) {
  return __uint_as_float(((unsigned int)h) << 16);
}
__device__ __forceinline__ short8 ld8(const unsigned short* p) {
  return *reinterpret_cast<const short8*>(p);
}
__device__ __forceinline__ unsigned char f2fp8(float v) {   // OCP e4m3 via HW cvt (RNE)
  return (unsigned char)__builtin_amdgcn_cvt_pk_fp8_f32(v, v, 0, false);
}
__device__ __forceinline__ int rowmap(int reg, int h) {     // 32x32 C/D row map
  return (reg & 3) + 8 * (reg >> 2) + 4 * h;
}

// ---------------- k_pre: z<8 -> h-tile of 4: transpose -> Xt, psum partials, dwconv
//                  (x staged ONCE as bf16, 1.5x halo overfetch vs 3x before);
//                  z==8 -> weight fp32->bf16 cast slice
__global__ __launch_bounds__(256, 2) void k_pre(
    const float* __restrict__ xs, const float* __restrict__ xo,
    const float* __restrict__ dww, const float* __restrict__ dwb,
    const float* __restrict__ bng, const float* __restrict__ bnb,
    const float* __restrict__ bnm, const float* __restrict__ bnv,
    const float* __restrict__ qw, const float* __restrict__ kvw,
    const float* __restrict__ ow, unsigned short* __restrict__ XtS,
    unsigned short* __restrict__ XtO, unsigned short* __restrict__ localT,
    float* __restrict__ psumA, unsigned short* __restrict__ Wb) {
  __shared__ unsigned short rb[6][64][68];   // stride 136B: us4 writes 8B-aligned;
  __shared__ unsigned short sb[64][68];      // transpose reads (stride 34 dw) 2-way free
  int tid = threadIdx.x;
  if (blockIdx.z == 8) {                     // weight cast: 64 blocks x 4096 elems
    int base = (blockIdx.x * 16 + blockIdx.y) * 4096 + tid * 4;
#pragma unroll
    for (int q = 0; q < 4; ++q) {
      int i = base + q * 1024;
      const float* src;
      if (i < 65536) src = qw + i;
      else if (i < 196608) src = kvw + (i - 65536);
      else src = ow + (i - 196608);
      f32x4 v = *reinterpret_cast<const f32x4*>(src);
      us4 r;
#pragma unroll
      for (int j = 0; j < 4; ++j) r[j] = f2bf(v[j]);
      *reinterpret_cast<us4*>(Wb + i) = r;
    }
    return;
  }
  int c0 = blockIdx.x * 64, h0 = blockIdx.y * 4;
  int b = blockIdx.z >> 1, which = blockIdx.z & 1;
  const float* src = which ? xo : xs;
  int rlo = which ? 1 : 0, rhi = which ? 4 : 5;
  for (int r = rlo; r <= rhi; ++r) {
    int hh = h0 + r - 1;
    bool ok = (hh >= 0 && hh < HH);
#pragma unroll
    for (int p = 0; p < 4; ++p) {
      int idx = p * 256 + tid;
      int cl = idx >> 4, w4 = (idx & 15) * 4;
      f32x4 v = {};
      if (ok)
        v = *reinterpret_cast<const f32x4*>(
            &src[(((size_t)(b * CC + c0 + cl)) * HH + hh) * WWD + w4]);
      us4 rr;
#pragma unroll
      for (int j = 0; j < 4; ++j) rr[j] = f2bf(v[j]);
      *reinterpret_cast<us4*>(&rb[r][cl][w4]) = rr;
    }
  }
  __syncthreads();
  // Xt transposed store: rows 1..4 = global h0..h0+3
  unsigned short* dst = which ? XtO : XtS;
  int cb = (tid & 15) * 4;
  for (int i = 0; i < 4; ++i) {
    int n0 = (h0 + i) * 64;
#pragma unroll
    for (int i2 = 0; i2 < 4; ++i2) {
      int wl = i2 * 16 + (tid >> 4);
      us4 r;
#pragma unroll
      for (int j = 0; j < 4; ++j) r[j] = rb[1 + i][cb + j][wl];
      *reinterpret_cast<us4*>(&dst[((size_t)b * NN + n0 + wl) * CC + c0 + cb]) = r;
    }
  }
  if (which) return;
  // channel-sum partials: thread (c=tid&63, row=tid>>6)
  {
    int c = tid & 63, i = tid >> 6;
    float s = 0.f;
    for (int w = 0; w < 64; ++w) s += bf2f(rb[1 + i][c][w]);
    psumA[((size_t)(b * 64 + h0 + i)) * CC + c0 + c] = s;
  }
  // depthwise 3x3 + BN + SiLU, 4 rows (h-halo pre-zeroed; w-edges predicated)
  int wq = tid >> 6, w = tid & 63;
  for (int i = 0; i < 4; ++i) {
    for (int p = 0; p < 16; ++p) {
      int cl = p * 4 + wq, c = c0 + cl;
      float acc = 0.f;
#pragma unroll
      for (int di = 0; di < 3; ++di)
#pragma unroll
        for (int dj = 0; dj < 3; ++dj) {
          int ww = w + dj - 1;
          float xv = (ww >= 0 && ww < 64) ? bf2f(rb[i + di][cl][ww]) : 0.f;
          acc = fmaf(xv, dww[c * 9 + di * 3 + dj], acc);
        }
      float y = acc + dwb[c];
      float sc = bng[c] * rsqrtf(bnv[c] + 1e-5f);
      float v = (y - bnm[c]) * sc + bnb[c];
      sb[cl][w] = f2bf(v / (1.f + __expf(-v)));
    }
    __syncthreads();
#pragma unroll
    for (int i2 = 0; i2 < 4; ++i2) {
      int wl = i2 * 16 + (tid >> 4);
      us4 r;
#pragma unroll
      for (int j = 0; j < 4; ++j) r[j] = sb[cb + j][wl];
      *reinterpret_cast<us4*>(
          &localT[((size_t)b * NN + (h0 + i) * 64 + wl) * CC + c0 + cb]) = r;
    }
    __syncthreads();
  }
}

// --------- fused Q,K,V projections -> fp8 outputs (LDS-transposed, coalesced);
//           + gate block (y==3). Q,K carry sqrt-split softmax scale (0.25 each).
__global__ __launch_bounds__(256, 4) void k_qkv(
    const unsigned short* __restrict__ XtS, const unsigned short* __restrict__ XtO,
    const unsigned short* __restrict__ Wb, const float* __restrict__ qb,
    const float* __restrict__ kvb, const float* __restrict__ psumA,
    const float* __restrict__ g1w, const float* __restrict__ g1b,
    const float* __restrict__ g2w, const float* __restrict__ g2b,
    unsigned char* __restrict__ Qt8, unsigned char* __restrict__ Kt8,
    unsigned char* __restrict__ Vv8, float* __restrict__ gate) {
  __shared__ unsigned short Xs[64][264];   // 33.8 KB; reused as fp8 transpose buffer
  int tid = threadIdx.x;
  int id = blockIdx.y;
  if (id == 3) {                            // gate (SE path), one working block
    if (blockIdx.x != 0 || blockIdx.z != 0) return;
    float* mf = (float*)&Xs[0][0];
    float* hpf = mf + 1024;
    int c = tid;
    for (int b4 = 0; b4 < 4; ++b4) {
      float s = 0.f;
      for (int hh = 0; hh < 64; ++hh) s += psumA[((size_t)(b4 * 64 + hh)) * CC + c];
      mf[b4 * 256 + c] = s * (1.f / 4096.f);
    }
    __syncthreads();
    for (int b4 = 0; b4 < 4; ++b4) {
      int j = tid >> 2, cq = tid & 3;
      float s = 0.f;
      for (int cc = cq * 64; cc < cq * 64 + 64; ++cc)
        s = fmaf(mf[b4 * 256 + cc], g1w[j * CC + cc], s);
      hpf[j * 5 + cq] = s;
      __syncthreads();
      if (tid < 64) {
        float hh = fmaxf(hpf[tid * 5] + hpf[tid * 5 + 1] + hpf[tid * 5 + 2] +
                             hpf[tid * 5 + 3] + g1b[tid], 0.f);
        float t = hh * g2w[tid];
        for (int off = 32; off; off >>= 1) t += __shfl_down(t, off, 64);
        if (tid == 0) gate[b4] = 1.f / (1.f + expf(-(t + g2b[0])));
      }
      __syncthreads();
    }
    return;
  }
  int n0 = blockIdx.x * 64, b = blockIdx.z;
  const unsigned short* Xt = (id == 0) ? XtS : XtO;
  const unsigned short* W = Wb + id * 65536;
  int wave = tid >> 6, lane = tid & 63, l31 = lane & 31, h = lane >> 5;
#pragma unroll
  for (int p = 0; p < 8; ++p) {
    int r = p * 8 + (tid >> 5), c = (tid & 31) * 8;
    *reinterpret_cast<uint4*>(&Xs[r][c]) =
        *reinterpret_cast<const uint4*>(Xt + ((size_t)b * NN + n0 + r) * CC + c);
  }
  __syncthreads();
  int o0 = wave * 64;
  f32x16 acc[4] = {};
  if (id < 2) {
#pragma unroll
    for (int t = 0; t < 16; ++t) {
      short8 a0 = ld8(&Xs[l31][t * 16 + h * 8]);
      short8 a1 = ld8(&Xs[32 + l31][t * 16 + h * 8]);
      short8 b0 = ld8(W + (size_t)(o0 + l31) * CC + t * 16 + h * 8);
      short8 b1 = ld8(W + (size_t)(o0 + 32 + l31) * CC + t * 16 + h * 8);
      acc[0] = __builtin_amdgcn_mfma_f32_32x32x16_bf16(a0, b0, acc[0], 0, 0, 0);
      acc[1] = __builtin_amdgcn_mfma_f32_32x32x16_bf16(a0, b1, acc[1], 0, 0, 0);
      acc[2] = __builtin_amdgcn_mfma_f32_32x32x16_bf16(a1, b0, acc[2], 0, 0, 0);
      acc[3] = __builtin_amdgcn_mfma_f32_32x32x16_bf16(a1, b1, acc[3], 0, 0, 0);
    }
    const float* bias = id ? kvb : qb;
    unsigned char* Out8 = id ? Kt8 : Qt8;
    __syncthreads();                        // Xs MFMA reads done
    unsigned char (*T8)[264] = reinterpret_cast<unsigned char(*)[264]>(&Xs[0][0]);
#pragma unroll
    for (int nt = 0; nt < 2; ++nt)
#pragma unroll
      for (int ot = 0; ot < 2; ++ot) {
        int o = o0 + ot * 32 + l31;
        float bv = bias[o];
#pragma unroll
        for (int reg = 0; reg < 16; ++reg) {
          int nl = nt * 32 + rowmap(reg, h);
          T8[nl][o] = f2fp8((acc[nt * 2 + ot][reg] + bv) * 0.25f);
        }
      }
    __syncthreads();
#pragma unroll
    for (int p = 0; p < 4; ++p) {
      int idx = p * 256 + tid, row = idx >> 4, cc = (idx & 15) * 16;
      ull a0 = *reinterpret_cast<const ull*>(&T8[row][cc]);
      ull a1 = *reinterpret_cast<const ull*>(&T8[row][cc + 8]);
      uint4 u;
      u.x = (unsigned)a0; u.y = (unsigned)(a0 >> 32);
      u.z = (unsigned)a1; u.w = (unsigned)(a1 >> 32);
      *reinterpret_cast<uint4*>(Out8 + ((size_t)b * NN + n0 + row) * CC + cc) = u;
    }
  } else {
    // V[o][n]
#pragma unroll
    for (int t = 0; t < 16; ++t) {
      short8 a0 = ld8(W + (size_t)(o0 + l31) * CC + t * 16 + h * 8);
      short8 a1 = ld8(W + (size_t)(o0 + 32 + l31) * CC + t * 16 + h * 8);
      short8 b0 = ld8(&Xs[l31][t * 16 + h * 8]);
      short8 b1 = ld8(&Xs[32 + l31][t * 16 + h * 8]);
      acc[0] = __builtin_amdgcn_mfma_f32_32x32x16_bf16(a0, b0, acc[0], 0, 0, 0);
      acc[1] = __builtin_amdgcn_mfma_f32_32x32x16_bf16(a0, b1, acc[1], 0, 0, 0);
      acc[2] = __builtin_amdgcn_mfma_f32_32x32x16_bf16(a1, b0, acc[2], 0, 0, 0);
      acc[3] = __builtin_amdgcn_mfma_f32_32x32x16_bf16(a1, b1, acc[3], 0, 0, 0);
    }
    __syncthreads();
    unsigned char (*V8)[72] = reinterpret_cast<unsigned char(*)[72]>(&Xs[0][0]);
#pragma unroll
    for (int ot = 0; ot < 2; ++ot)
#pragma unroll
      for (int nt = 0; nt < 2; ++nt)
#pragma unroll
        for (int reg = 0; reg < 16; ++reg) {
          int o = o0 + ot * 32 + rowmap(reg, h);
          int nl = nt * 32 + l31;
          V8[o][nl] = f2fp8(acc[ot * 2 + nt][reg] + kvb[CC + o]);
        }
    __syncthreads();
#pragma unroll
    for (int p = 0; p < 4; ++p) {
      int idx = p * 256 + tid, o = idx >> 2, mm = (idx & 3) * 16;
      ull a0 = *reinterpret_cast<const ull*>(&V8[o][mm]);
      ull a1 = *reinterpret_cast<const ull*>(&V8[o][mm + 8]);
      uint4 u;
      u.x = (unsigned)a0; u.y = (unsigned)(a0 >> 32);
      u.z = (unsigned)a1; u.w = (unsigned)(a1 >> 32);
      *reinterpret_cast<uint4*>(Vv8 + ((size_t)b * CC + o) * NN + n0 + mm) = u;
    }
  }
}

// ------------- flash attention, fp8 e4m3 (Q,K,V,P in LDS) — round-6 proven structure
__global__ __launch_bounds__(256, 3) void k_flash8(
    const unsigned char* __restrict__ Qt8, const unsigned char* __restrict__ Kt8,
    const unsigned char* __restrict__ Vv8, const unsigned short* __restrict__ localT,
    const float* __restrict__ gate, unsigned short* __restrict__ Opart16,
    float* __restrict__ Lpart, unsigned short* __restrict__ fusedT) {
  __shared__ unsigned char Ks8[64][264];
  __shared__ unsigned char Vs8[256][72];
  __shared__ unsigned char Ps8[64][72];
  __shared__ float lred[2][64];
  __shared__ float ltot[64];
  // XCD swizzle: b = x&3 -> each XCD pinned to one b; K+V fp8 = 2 MB, L2-resident
  int b = blockIdx.x & 3, n0 = (blockIdx.x >> 2) * 64;
  int sp = blockIdx.y, nsp = gridDim.y;
  int tid = threadIdx.x, wave = tid >> 6, lane = tid & 63, l31 = lane & 31, h = lane >> 5;
  int rw = wave & 1, cw = wave >> 1;
  const unsigned char* qp = Qt8 + ((size_t)b * NN + n0 + rw * 32 + l31) * CC + h * 8;
  long qf[16];
#pragma unroll
  for (int t = 0; t < 16; ++t) qf[t] = *reinterpret_cast<const long*>(qp + t * 16);
  f32x16 O[4] = {};
  float lacc[16] = {};
  int m_lo = (64 * sp) / nsp, m_hi = (64 * (sp + 1)) / nsp;
  for (int mt = m_lo; mt < m_hi; ++mt) {
    int m0 = mt * 64;
    __syncthreads();
#pragma unroll
    for (int p = 0; p < 4; ++p) {
      int idx = p * 256 + tid, m = idx >> 4, cc = (idx & 15) * 16;
      const ull* gp = reinterpret_cast<const ull*>(Kt8 + ((size_t)b * NN + m0 + m) * CC + cc);
      ull a0 = gp[0], a1 = gp[1];
      *reinterpret_cast<ull*>(&Ks8[m][cc]) = a0;
      *reinterpret_cast<ull*>(&Ks8[m][cc + 8]) = a1;
    }
#pragma unroll
    for (int p = 0; p < 4; ++p) {
      int idx = p * 256 + tid, c = idx >> 2, mm = (idx & 3) * 16;
      const ull* gp = reinterpret_cast<const ull*>(Vv8 + ((size_t)b * CC + c) * NN + m0 + mm);
      ull a0 = gp[0], a1 = gp[1];
      *reinterpret_cast<ull*>(&Vs8[c][mm]) = a0;
      *reinterpret_cast<ull*>(&Vs8[c][mm + 8]) = a1;
    }
    __syncthreads();
    f32x16 S = {};
#pragma unroll
    for (int t = 0; t < 16; ++t) {
      long kf = *reinterpret_cast<const long*>(&Ks8[cw * 32 + l31][t * 16 + h * 8]);
      S = __builtin_amdgcn_mfma_f32_32x32x16_fp8_fp8(qf[t], kf, S, 0, 0, 0);
    }
#pragma unroll
    for (int reg = 0; reg < 16; ++reg) {
      float p = __builtin_exp2f(S[reg] * LOG2E);
      lacc[reg] += p;
      Ps8[rw * 32 + rowmap(reg, h)][cw * 32 + l31] = f2fp8(p);
    }
    __syncthreads();
#pragma unroll
    for (int t = 0; t < 4; ++t) {
      long pf = *reinterpret_cast<const long*>(&Ps8[rw * 32 + l31][t * 16 + h * 8]);
#pragma unroll
      for (int ct = 0; ct < 4; ++ct) {
        long vf = *reinterpret_cast<const long*>(&Vs8[cw * 128 + ct * 32 + l31][t * 16 + h * 8]);
        O[ct] = __builtin_amdgcn_mfma_f32_32x32x16_fp8_fp8(pf, vf, O[ct], 0, 0, 0);
      }
    }
  }
#pragma unroll
  for (int reg = 0; reg < 16; ++reg) {
    float v = lacc[reg];
#pragma unroll
    for (int msk = 1; msk < 32; msk <<= 1) v += __shfl_xor(v, msk, 64);
    lacc[reg] = v;
  }
  __syncthreads();
#pragma unroll
  for (int g = 0; g < 16; ++g)
    if (l31 == g) lred[cw][rw * 32 + rowmap(g, h)] = lacc[g];
  __syncthreads();
  size_t obase2 = (size_t)(b * nsp + sp) * NN;
  if (nsp == 1) {
    if (tid < 64) ltot[tid] = lred[0][tid] + lred[1][tid];
    __syncthreads();
    float gv = gate[b];
    float inv[16];
#pragma unroll
    for (int reg = 0; reg < 16; ++reg)
      inv[reg] = gv / ltot[rw * 32 + rowmap(reg, h)];
#pragma unroll
    for (int ct = 0; ct < 4; ++ct)
#pragma unroll
      for (int reg = 0; reg < 16; ++reg) {
        int n = n0 + rw * 32 + rowmap(reg, h);
        int c = cw * 128 + ct * 32 + l31;
        size_t idx = ((size_t)b * NN + n) * CC + c;
        fusedT[idx] = f2bf(bf2f(localT[idx]) + O[ct][reg] * inv[reg]);
      }
  } else {
    if (tid < 64) Lpart[obase2 + n0 + tid] = lred[0][tid] + lred[1][tid];
#pragma unroll
    for (int ct = 0; ct < 4; ++ct)
#pragma unroll
      for (int reg = 0; reg < 16; ++reg) {
        int n = n0 + rw * 32 + rowmap(reg, h);
        int c = cw * 128 + ct * 32 + l31;
        Opart16[(obase2 + n) * CC + c] = f2bf(O[ct][reg]);
      }
  }
}

// --------- out projection with fused split-combine (Opart bf16)
__global__ __launch_bounds__(256, 4) void k_out(
    const unsigned short* __restrict__ W, const float* __restrict__ ob,
    const float* __restrict__ gate, const unsigned short* __restrict__ localT,
    const unsigned short* __restrict__ Opart16, const float* __restrict__ Lpart,
    const unsigned short* __restrict__ fusedT, float* __restrict__ out, int nsp) {
  __shared__ unsigned short Xs[64][264];
  int n0 = blockIdx.x * 64, o0 = blockIdx.y * 128, b = blockIdx.z;
  int tid = threadIdx.x, wave = tid >> 6, lane = tid & 63, l31 = lane & 31, h = lane >> 5;
  if (Opart16) {
    float gv = gate[b];
#pragma unroll
    for (int p = 0; p < 8; ++p) {
      int r = p * 8 + (tid >> 5), cc = (tid & 31) * 8;
      int n = n0 + r;
      float lsum = 0.f;
      for (int sp = 0; sp < nsp; ++sp) lsum += Lpart[(size_t)(b * nsp + sp) * NN + n];
      float g = gv / lsum;
      float ov[8] = {};
      for (int sp = 0; sp < nsp; ++sp) {
        short8 x = ld8(Opart16 + ((size_t)(b * nsp + sp) * NN + n) * CC + cc);
#pragma unroll
        for (int j = 0; j < 8; ++j) ov[j] += bf2f(((unsigned short*)&x)[j]);
      }
      const unsigned short* lp = localT + ((size_t)b * NN + n) * CC + cc;
      short8 lv = ld8(lp);
      us4 r0, r1;
#pragma unroll
      for (int j = 0; j < 4; ++j) {
        r0[j] = f2bf(bf2f(((unsigned short*)&lv)[j]) + ov[j] * g);
        r1[j] = f2bf(bf2f(((unsigned short*)&lv)[j + 4]) + ov[j + 4] * g);
      }
      *reinterpret_cast<us4*>(&Xs[r][cc]) = r0;
      *reinterpret_cast<us4*>(&Xs[r][cc + 4]) = r1;
    }
  } else {
#pragma unroll
    for (int p = 0; p < 8; ++p) {
      int r = p * 8 + (tid >> 5), c = (tid & 31) * 8;
      *reinterpret_cast<uint4*>(&Xs[r][c]) =
          *reinterpret_cast<const uint4*>(fusedT + ((size_t)b * NN + n0 + r) * CC + c);
    }
  }
  int obase = o0 + wave * 32;
  short8 af[16];
#pragma unroll
  for (int t = 0; t < 16; ++t) af[t] = ld8(W + (size_t)(obase + l31) * CC + t * 16 + h * 8);
  __syncthreads();
  f32x16 acc[2] = {};
#pragma unroll
  for (int t = 0; t < 16; ++t) {
    short8 b0 = ld8(&Xs[l31][t * 16 + h * 8]);
    short8 b1 = ld8(&Xs[32 + l31][t * 16 + h * 8]);
    acc[0] = __builtin_amdgcn_mfma_f32_32x32x16_bf16(af[t], b0, acc[0], 0, 0, 0);
    acc[1] = __builtin_amdgcn_mfma_f32_32x32x16_bf16(af[t], b1, acc[1], 0, 0, 0);
  }
#pragma unroll
  for (int nt = 0; nt < 2; ++nt)
#pragma unroll
    for (int reg = 0; reg < 16; ++reg) {
      int o = obase + rowmap(reg, h);
      int n = n0 + nt * 32 + l31;
      out[((size_t)b * CC + o) * NN + n] = acc[nt][reg] + ob[o];
    }
}

// ---------------------------------------------------------------------------- launch
extern "C" void kernel_launch(void* const* d_in, const int* in_sizes, int n_in,
                              void* d_out, int out_size, void* d_ws, size_t ws_size,
                              hipStream_t stream) {
  const float* xs  = (const float*)d_in[0];
  const float* xo  = (const float*)d_in[1];
  const float* qw  = (const float*)d_in[2];
  const float* qb  = (const float*)d_in[3];
  const float* kvw = (const float*)d_in[4];
  const float* kvb = (const float*)d_in[5];
  const float* g1w = (const float*)d_in[6];
  const float* g1b = (const float*)d_in[7];
  const float* g2w = (const float*)d_in[8];
  const float* g2b = (const float*)d_in[9];
  const float* dww = (const float*)d_in[10];
  const float* dwb = (const float*)d_in[11];
  const float* bng = (const float*)d_in[12];
  const float* bnb = (const float*)d_in[13];
  const float* bnm = (const float*)d_in[14];
  const float* bnv = (const float*)d_in[15];
  const float* ow  = (const float*)d_in[16];
  const float* ob  = (const float*)d_in[17];
  float* out = (float*)d_out;
  char* ws = (char*)d_ws;

  const size_t SZ  = (size_t)BB * NN * CC * 2;            // 8 MB bf16 tensor
  const size_t SZ8 = (size_t)BB * NN * CC;                // 4 MB fp8 tensor
  unsigned short* XtS    = (unsigned short*)(ws);
  unsigned short* XtO    = (unsigned short*)(ws + SZ);
  unsigned short* localT = (unsigned short*)(ws + 2 * SZ);
  unsigned char*  Qt8    = (unsigned char*)(ws + 3 * SZ);
  unsigned char*  Kt8    = (unsigned char*)(ws + 3 * SZ + SZ8);
  unsigned char*  Vv8    = (unsigned char*)(ws + 3 * SZ + 2 * SZ8);
  unsigned short* Wb     = (unsigned short*)(ws + 3 * SZ + 3 * SZ8);   // 512 KB
  float* psumA = (float*)(ws + 3 * SZ + 3 * SZ8 + 524288);             // 256 KB
  float* gate  = (float*)(ws + 3 * SZ + 3 * SZ8 + 524288 + 262144);    // 16 B
  size_t tail  = 3 * SZ + 3 * SZ8 + 524288 + 262144 + 4096;
  float* Lpart = (float*)(ws + tail);                                  // 256 KB
  unsigned short* Opart16 = (unsigned short*)(ws + tail + 262144);     // nsp*8 MB
  unsigned short* fusedT = XtS;                                        // dead after k_qkv

  size_t base = tail + 262144;
  int S = 1;
  if (ws_size >= base + 3ull * SZ) S = 3;          // 768 blocks = 3/CU
  else if (ws_size >= base + 2ull * SZ) S = 2;

  k_pre<<<dim3(4, 16, 9), 256, 0, stream>>>(xs, xo, dww, dwb, bng, bnb, bnm, bnv,
                                            qw, kvw, ow, XtS, XtO, localT, psumA, Wb);
  k_qkv<<<dim3(64, 4, 4), 256, 0, stream>>>(XtS, XtO, Wb, qb, kvb, psumA,
                                            g1w, g1b, g2w, g2b, Qt8, Kt8, Vv8, gate);
  k_flash8<<<dim3(256, S), 256, 0, stream>>>(Qt8, Kt8, Vv8, localT, gate, Opart16,
                                             Lpart, fusedT);
  k_out<<<dim3(64, 2, 4), 256, 0, stream>>>(Wb + 196608, ob, gate, localT,
                                            S > 1 ? Opart16 : nullptr, Lpart, fusedT,
                                            out, S);
}

// Round 9
// 254.142 us; speedup vs baseline: 1.2825x; 1.0691x over previous
//
#include <hip/hip_runtime.h>
#include <stdint.h>

#define BB 4
#define CC 256
#define HH 64
#define WWD 64
#define NN 4096
#define LOG2E 1.4426950408889634f

typedef __attribute__((ext_vector_type(8))) short short8;
typedef __attribute__((ext_vector_type(4))) float f32x4;
typedef __attribute__((ext_vector_type(16))) float f32x16;
typedef __attribute__((ext_vector_type(4))) unsigned short us4;
typedef unsigned long long ull;

__device__ __forceinline__ unsigned short f2bf(float f) {
  unsigned int u = __float_as_uint(f);
  u += 0x7fffu + ((u >> 16) & 1u);          // RNE
  return (unsigned short)(u >> 16);
}
__device__ __forceinline__ float bf2f(unsigned short h) {
  return __uint_as_float(((unsigned int)h) << 16);
}
__device__ __forceinline__ short8 ld8(const unsigned short* p) {
  return *reinterpret_cast<const short8*>(p);
}
__device__ __forceinline__ unsigned char f2fp8(float v) {   // OCP e4m3 via HW cvt (RNE)
  return (unsigned char)__builtin_amdgcn_cvt_pk_fp8_f32(v, v, 0, false);
}
__device__ __forceinline__ int rowmap(int reg, int h) {     // 32x32 C/D row map
  return (reg & 3) + 8 * (reg >> 2) + 4 * h;
}

// ---------------- k_pre (round-6 proven): z<8 -> transpose (+psum, +dwconv for xs);
//                  z==8 -> weight fp32->bf16 cast slice
__global__ __launch_bounds__(256, 2) void k_pre(
    const float* __restrict__ xs, const float* __restrict__ xo,
    const float* __restrict__ dww, const float* __restrict__ dwb,
    const float* __restrict__ bng, const float* __restrict__ bnb,
    const float* __restrict__ bnm, const float* __restrict__ bnv,
    const float* __restrict__ qw, const float* __restrict__ kvw,
    const float* __restrict__ ow, unsigned short* __restrict__ XtS,
    unsigned short* __restrict__ XtO, unsigned short* __restrict__ localT,
    float* __restrict__ psumA, unsigned short* __restrict__ Wb) {
  __shared__ float rb3[3][64][67];
  __shared__ unsigned short sb[64][67];
  int tid = threadIdx.x;
  if (blockIdx.z == 8) {                    // weight cast
    int i = (blockIdx.x * 64 + blockIdx.y) * 1024 + tid * 4;
    const float* src;
    if (i < 65536) src = qw + i;
    else if (i < 196608) src = kvw + (i - 65536);
    else src = ow + (i - 196608);
    f32x4 v = *reinterpret_cast<const f32x4*>(src);
    us4 r;
#pragma unroll
    for (int j = 0; j < 4; ++j) r[j] = f2bf(v[j]);
    *reinterpret_cast<us4*>(Wb + i) = r;
    return;
  }
  int c0 = blockIdx.x * 64, h = blockIdx.y;
  int b = blockIdx.z >> 1, which = blockIdx.z & 1;
  const float* src = which ? xo : xs;
  int wq = tid >> 6, w = tid & 63;
  int dlo = which ? 1 : 0, dhi = which ? 1 : 2;
  for (int d = dlo; d <= dhi; ++d) {
    int hh = h + d - 1;
    bool ok = (hh >= 0 && hh < HH);
#pragma unroll
    for (int p = 0; p < 4; ++p) {
      int idx = p * 256 + tid;
      int cl = idx >> 4, ws4 = (idx & 15) * 4;
      f32x4 v = {};
      if (ok)
        v = *reinterpret_cast<const f32x4*>(
            &src[(((size_t)(b * CC + c0 + cl)) * HH + hh) * WWD + ws4]);
#pragma unroll
      for (int j = 0; j < 4; ++j) rb3[d][cl][ws4 + 1 + j] = v[j];
    }
    if (tid < 64) { rb3[d][tid][0] = 0.f; rb3[d][tid][65] = 0.f; }
  }
  __syncthreads();
  // transpose-store middle row -> Xt
  unsigned short* dst = which ? XtO : XtS;
  int n0 = h * 64, cb = (tid & 15) * 4;
#pragma unroll
  for (int i = 0; i < 4; ++i) {
    int wl = i * 16 + (tid >> 4);
    us4 r;
#pragma unroll
    for (int j = 0; j < 4; ++j) r[j] = f2bf(rb3[1][cb + j][wl + 1]);
    *reinterpret_cast<us4*>(&dst[((size_t)b * NN + n0 + wl) * CC + c0 + cb]) = r;
  }
  if (which) return;
  if (tid < 64) {                           // channel-sum partial
    float s = 0.f;
    for (int ww = 0; ww < 64; ++ww) s += rb3[1][tid][ww + 1];
    psumA[((size_t)(b * 64 + h)) * CC + c0 + tid] = s;
  }
  // depthwise 3x3 + BN + SiLU
  for (int p = 0; p < 16; ++p) {
    int cl = p * 4 + wq, c = c0 + cl;
    float acc = 0.f;
#pragma unroll
    for (int di = 0; di < 3; ++di)
#pragma unroll
      for (int dj = 0; dj < 3; ++dj)
        acc = fmaf(rb3[di][cl][w + dj], dww[c * 9 + di * 3 + dj], acc);
    float y = acc + dwb[c];
    float sc = bng[c] * rsqrtf(bnv[c] + 1e-5f);
    float v = (y - bnm[c]) * sc + bnb[c];
    sb[cl][w] = f2bf(v / (1.f + __expf(-v)));
  }
  __syncthreads();
#pragma unroll
  for (int i = 0; i < 4; ++i) {
    int wl = i * 16 + (tid >> 4);
    us4 r;
#pragma unroll
    for (int j = 0; j < 4; ++j) r[j] = sb[cb + j][wl];
    *reinterpret_cast<us4*>(&localT[((size_t)b * NN + h * WWD + wl) * CC + c0 + cb]) = r;
  }
}

// --------- projections -> fp8. id0: Q (XtS). id1: K THEN V (XtO staged once,
// acc regs reused, TB transpose buffer keeps Xs intact). id2: gate (1 block).
// Q,K carry sqrt-split softmax scale (0.25 each).
__global__ __launch_bounds__(256, 3) void k_qkv(
    const unsigned short* __restrict__ XtS, const unsigned short* __restrict__ XtO,
    const unsigned short* __restrict__ Wb, const float* __restrict__ qb,
    const float* __restrict__ kvb, const float* __restrict__ psumA,
    const float* __restrict__ g1w, const float* __restrict__ g1b,
    const float* __restrict__ g2w, const float* __restrict__ g2b,
    unsigned char* __restrict__ Qt8, unsigned char* __restrict__ Kt8,
    unsigned char* __restrict__ Vv8, float* __restrict__ gate) {
  __shared__ unsigned short Xs[64][264];   // 33.8 KB input tile
  __shared__ unsigned char TB[18464];      // transpose buffer: T8[64][264] or V8[256][72]
  int tid = threadIdx.x;
  int id = blockIdx.y;
  if (id == 2) {                            // gate (SE path), one working block
    if (blockIdx.x != 0 || blockIdx.z != 0) return;
    float* mf = (float*)&Xs[0][0];
    float* hpf = mf + 1024;
    int c = tid;
    for (int b4 = 0; b4 < 4; ++b4) {
      float s = 0.f;
      for (int hh = 0; hh < 64; ++hh) s += psumA[((size_t)(b4 * 64 + hh)) * CC + c];
      mf[b4 * 256 + c] = s * (1.f / 4096.f);
    }
    __syncthreads();
    for (int b4 = 0; b4 < 4; ++b4) {
      int j = tid >> 2, cq = tid & 3;
      float s = 0.f;
      for (int cc = cq * 64; cc < cq * 64 + 64; ++cc)
        s = fmaf(mf[b4 * 256 + cc], g1w[j * CC + cc], s);
      hpf[j * 5 + cq] = s;
      __syncthreads();
      if (tid < 64) {
        float hh = fmaxf(hpf[tid * 5] + hpf[tid * 5 + 1] + hpf[tid * 5 + 2] +
                             hpf[tid * 5 + 3] + g1b[tid], 0.f);
        float t = hh * g2w[tid];
        for (int off = 32; off; off >>= 1) t += __shfl_down(t, off, 64);
        if (tid == 0) gate[b4] = 1.f / (1.f + expf(-(t + g2b[0])));
      }
      __syncthreads();
    }
    return;
  }
  int n0 = blockIdx.x * 64, b = blockIdx.z;
  const unsigned short* Xt = (id == 0) ? XtS : XtO;
  int wave = tid >> 6, lane = tid & 63, l31 = lane & 31, h = lane >> 5;
#pragma unroll
  for (int p = 0; p < 8; ++p) {
    int r = p * 8 + (tid >> 5), c = (tid & 31) * 8;
    *reinterpret_cast<uint4*>(&Xs[r][c]) =
        *reinterpret_cast<const uint4*>(Xt + ((size_t)b * NN + n0 + r) * CC + c);
  }
  __syncthreads();
  int o0 = wave * 64;
  unsigned char (*T8)[264] = reinterpret_cast<unsigned char(*)[264]>(&TB[0]);

  // ---- pass 1: Out[n][o] GEMM (Q for id0, K for id1), fp8-transposed store
  {
    const unsigned short* W = Wb + id * 65536;          // qw or kvw-K
    const float* bias = id ? kvb : qb;
    unsigned char* Out8 = id ? Kt8 : Qt8;
    f32x16 acc[4] = {};
#pragma unroll
    for (int t = 0; t < 16; ++t) {
      short8 a0 = ld8(&Xs[l31][t * 16 + h * 8]);
      short8 a1 = ld8(&Xs[32 + l31][t * 16 + h * 8]);
      short8 b0 = ld8(W + (size_t)(o0 + l31) * CC + t * 16 + h * 8);
      short8 b1 = ld8(W + (size_t)(o0 + 32 + l31) * CC + t * 16 + h * 8);
      acc[0] = __builtin_amdgcn_mfma_f32_32x32x16_bf16(a0, b0, acc[0], 0, 0, 0);
      acc[1] = __builtin_amdgcn_mfma_f32_32x32x16_bf16(a0, b1, acc[1], 0, 0, 0);
      acc[2] = __builtin_amdgcn_mfma_f32_32x32x16_bf16(a1, b0, acc[2], 0, 0, 0);
      acc[3] = __builtin_amdgcn_mfma_f32_32x32x16_bf16(a1, b1, acc[3], 0, 0, 0);
    }
#pragma unroll
    for (int nt = 0; nt < 2; ++nt)
#pragma unroll
      for (int ot = 0; ot < 2; ++ot) {
        int o = o0 + ot * 32 + l31;
        float bv = bias[o];
#pragma unroll
        for (int reg = 0; reg < 16; ++reg) {
          int nl = nt * 32 + rowmap(reg, h);
          T8[nl][o] = f2fp8((acc[nt * 2 + ot][reg] + bv) * 0.25f);
        }
      }
    __syncthreads();
#pragma unroll
    for (int p = 0; p < 4; ++p) {
      int idx = p * 256 + tid, row = idx >> 4, cc = (idx & 15) * 16;
      ull a0 = *reinterpret_cast<const ull*>(&T8[row][cc]);
      ull a1 = *reinterpret_cast<const ull*>(&T8[row][cc + 8]);
      uint4 u;
      u.x = (unsigned)a0; u.y = (unsigned)(a0 >> 32);
      u.z = (unsigned)a1; u.w = (unsigned)(a1 >> 32);
      *reinterpret_cast<uint4*>(Out8 + ((size_t)b * NN + n0 + row) * CC + cc) = u;
    }
  }
  if (id == 0) return;

  // ---- pass 2 (id1 only): V[o][n] GEMM from the SAME Xs tile
  __syncthreads();                          // all TB reads (K store) done
  {
    const unsigned short* W = Wb + 131072;  // kvw-V
    f32x16 acc[4] = {};
#pragma unroll
    for (int t = 0; t < 16; ++t) {
      short8 a0 = ld8(W + (size_t)(o0 + l31) * CC + t * 16 + h * 8);
      short8 a1 = ld8(W + (size_t)(o0 + 32 + l31) * CC + t * 16 + h * 8);
      short8 b0 = ld8(&Xs[l31][t * 16 + h * 8]);
      short8 b1 = ld8(&Xs[32 + l31][t * 16 + h * 8]);
      acc[0] = __builtin_amdgcn_mfma_f32_32x32x16_bf16(a0, b0, acc[0], 0, 0, 0);
      acc[1] = __builtin_amdgcn_mfma_f32_32x32x16_bf16(a0, b1, acc[1], 0, 0, 0);
      acc[2] = __builtin_amdgcn_mfma_f32_32x32x16_bf16(a1, b0, acc[2], 0, 0, 0);
      acc[3] = __builtin_amdgcn_mfma_f32_32x32x16_bf16(a1, b1, acc[3], 0, 0, 0);
    }
    unsigned char (*V8)[72] = reinterpret_cast<unsigned char(*)[72]>(&TB[0]);
#pragma unroll
    for (int ot = 0; ot < 2; ++ot)
#pragma unroll
      for (int nt = 0; nt < 2; ++nt)
#pragma unroll
        for (int reg = 0; reg < 16; ++reg) {
          int o = o0 + ot * 32 + rowmap(reg, h);
          int nl = nt * 32 + l31;
          V8[o][nl] = f2fp8(acc[ot * 2 + nt][reg] + kvb[CC + o]);
        }
    __syncthreads();
#pragma unroll
    for (int p = 0; p < 4; ++p) {
      int idx = p * 256 + tid, o = idx >> 2, mm = (idx & 3) * 16;
      ull a0 = *reinterpret_cast<const ull*>(&V8[o][mm]);
      ull a1 = *reinterpret_cast<const ull*>(&V8[o][mm + 8]);
      uint4 u;
      u.x = (unsigned)a0; u.y = (unsigned)(a0 >> 32);
      u.z = (unsigned)a1; u.w = (unsigned)(a1 >> 32);
      *reinterpret_cast<uint4*>(Vv8 + ((size_t)b * CC + o) * NN + n0 + mm) = u;
    }
  }
}

// ------------- flash attention, fp8 e4m3 (Q,K,V,P in LDS) — round-6/8 proven structure
__global__ __launch_bounds__(256, 3) void k_flash8(
    const unsigned char* __restrict__ Qt8, const unsigned char* __restrict__ Kt8,
    const unsigned char* __restrict__ Vv8, const unsigned short* __restrict__ localT,
    const float* __restrict__ gate, unsigned short* __restrict__ Opart16,
    float* __restrict__ Lpart, unsigned short* __restrict__ fusedT) {
  __shared__ unsigned char Ks8[64][264];
  __shared__ unsigned char Vs8[256][72];
  __shared__ unsigned char Ps8[64][72];
  __shared__ float lred[2][64];
  __shared__ float ltot[64];
  // XCD swizzle: b = x&3 -> each XCD pinned to one b; K+V fp8 = 2 MB, L2-resident
  int b = blockIdx.x & 3, n0 = (blockIdx.x >> 2) * 64;
  int sp = blockIdx.y, nsp = gridDim.y;
  int tid = threadIdx.x, wave = tid >> 6, lane = tid & 63, l31 = lane & 31, h = lane >> 5;
  int rw = wave & 1, cw = wave >> 1;
  const unsigned char* qp = Qt8 + ((size_t)b * NN + n0 + rw * 32 + l31) * CC + h * 8;
  long qf[16];
#pragma unroll
  for (int t = 0; t < 16; ++t) qf[t] = *reinterpret_cast<const long*>(qp + t * 16);
  f32x16 O[4] = {};
  float lacc[16] = {};
  int m_lo = (64 * sp) / nsp, m_hi = (64 * (sp + 1)) / nsp;
  for (int mt = m_lo; mt < m_hi; ++mt) {
    int m0 = mt * 64;
    __syncthreads();
#pragma unroll
    for (int p = 0; p < 4; ++p) {
      int idx = p * 256 + tid, m = idx >> 4, cc = (idx & 15) * 16;
      const ull* gp = reinterpret_cast<const ull*>(Kt8 + ((size_t)b * NN + m0 + m) * CC + cc);
      ull a0 = gp[0], a1 = gp[1];
      *reinterpret_cast<ull*>(&Ks8[m][cc]) = a0;
      *reinterpret_cast<ull*>(&Ks8[m][cc + 8]) = a1;
    }
#pragma unroll
    for (int p = 0; p < 4; ++p) {
      int idx = p * 256 + tid, c = idx >> 2, mm = (idx & 3) * 16;
      const ull* gp = reinterpret_cast<const ull*>(Vv8 + ((size_t)b * CC + c) * NN + m0 + mm);
      ull a0 = gp[0], a1 = gp[1];
      *reinterpret_cast<ull*>(&Vs8[c][mm]) = a0;
      *reinterpret_cast<ull*>(&Vs8[c][mm + 8]) = a1;
    }
    __syncthreads();
    f32x16 S = {};
#pragma unroll
    for (int t = 0; t < 16; ++t) {
      long kf = *reinterpret_cast<const long*>(&Ks8[cw * 32 + l31][t * 16 + h * 8]);
      S = __builtin_amdgcn_mfma_f32_32x32x16_fp8_fp8(qf[t], kf, S, 0, 0, 0);
    }
#pragma unroll
    for (int reg = 0; reg < 16; ++reg) {
      float p = __builtin_exp2f(S[reg] * LOG2E);
      lacc[reg] += p;
      Ps8[rw * 32 + rowmap(reg, h)][cw * 32 + l31] = f2fp8(p);
    }
    __syncthreads();
#pragma unroll
    for (int t = 0; t < 4; ++t) {
      long pf = *reinterpret_cast<const long*>(&Ps8[rw * 32 + l31][t * 16 + h * 8]);
#pragma unroll
      for (int ct = 0; ct < 4; ++ct) {
        long vf = *reinterpret_cast<const long*>(&Vs8[cw * 128 + ct * 32 + l31][t * 16 + h * 8]);
        O[ct] = __builtin_amdgcn_mfma_f32_32x32x16_fp8_fp8(pf, vf, O[ct], 0, 0, 0);
      }
    }
  }
#pragma unroll
  for (int reg = 0; reg < 16; ++reg) {
    float v = lacc[reg];
#pragma unroll
    for (int msk = 1; msk < 32; msk <<= 1) v += __shfl_xor(v, msk, 64);
    lacc[reg] = v;
  }
  __syncthreads();
#pragma unroll
  for (int g = 0; g < 16; ++g)
    if (l31 == g) lred[cw][rw * 32 + rowmap(g, h)] = lacc[g];
  __syncthreads();
  size_t obase2 = (size_t)(b * nsp + sp) * NN;
  if (nsp == 1) {
    if (tid < 64) ltot[tid] = lred[0][tid] + lred[1][tid];
    __syncthreads();
    float gv = gate[b];
    float inv[16];
#pragma unroll
    for (int reg = 0; reg < 16; ++reg)
      inv[reg] = gv / ltot[rw * 32 + rowmap(reg, h)];
#pragma unroll
    for (int ct = 0; ct < 4; ++ct)
#pragma unroll
      for (int reg = 0; reg < 16; ++reg) {
        int n = n0 + rw * 32 + rowmap(reg, h);
        int c = cw * 128 + ct * 32 + l31;
        size_t idx = ((size_t)b * NN + n) * CC + c;
        fusedT[idx] = f2bf(bf2f(localT[idx]) + O[ct][reg] * inv[reg]);
      }
  } else {
    if (tid < 64) Lpart[obase2 + n0 + tid] = lred[0][tid] + lred[1][tid];
#pragma unroll
    for (int ct = 0; ct < 4; ++ct)
#pragma unroll
      for (int reg = 0; reg < 16; ++reg) {
        int n = n0 + rw * 32 + rowmap(reg, h);
        int c = cw * 128 + ct * 32 + l31;
        Opart16[(obase2 + n) * CC + c] = f2bf(O[ct][reg]);
      }
  }
}

// --------- out projection with fused split-combine (Opart bf16)
__global__ __launch_bounds__(256, 4) void k_out(
    const unsigned short* __restrict__ W, const float* __restrict__ ob,
    const float* __restrict__ gate, const unsigned short* __restrict__ localT,
    const unsigned short* __restrict__ Opart16, const float* __restrict__ Lpart,
    const unsigned short* __restrict__ fusedT, float* __restrict__ out, int nsp) {
  __shared__ unsigned short Xs[64][264];
  int n0 = blockIdx.x * 64, o0 = blockIdx.y * 128, b = blockIdx.z;
  int tid = threadIdx.x, wave = tid >> 6, lane = tid & 63, l31 = lane & 31, h = lane >> 5;
  if (Opart16) {
    float gv = gate[b];
#pragma unroll
    for (int p = 0; p < 8; ++p) {
      int r = p * 8 + (tid >> 5), cc = (tid & 31) * 8;
      int n = n0 + r;
      float lsum = 0.f;
      for (int sp = 0; sp < nsp; ++sp) lsum += Lpart[(size_t)(b * nsp + sp) * NN + n];
      float g = gv / lsum;
      float ov[8] = {};
      for (int sp = 0; sp < nsp; ++sp) {
        short8 x = ld8(Opart16 + ((size_t)(b * nsp + sp) * NN + n) * CC + cc);
#pragma unroll
        for (int j = 0; j < 8; ++j) ov[j] += bf2f(((unsigned short*)&x)[j]);
      }
      const unsigned short* lp = localT + ((size_t)b * NN + n) * CC + cc;
      short8 lv = ld8(lp);
      us4 r0, r1;
#pragma unroll
      for (int j = 0; j < 4; ++j) {
        r0[j] = f2bf(bf2f(((unsigned short*)&lv)[j]) + ov[j] * g);
        r1[j] = f2bf(bf2f(((unsigned short*)&lv)[j + 4]) + ov[j + 4] * g);
      }
      *reinterpret_cast<us4*>(&Xs[r][cc]) = r0;
      *reinterpret_cast<us4*>(&Xs[r][cc + 4]) = r1;
    }
  } else {
#pragma unroll
    for (int p = 0; p < 8; ++p) {
      int r = p * 8 + (tid >> 5), c = (tid & 31) * 8;
      *reinterpret_cast<uint4*>(&Xs[r][c]) =
          *reinterpret_cast<const uint4*>(fusedT + ((size_t)b * NN + n0 + r) * CC + c);
    }
  }
  int obase = o0 + wave * 32;
  short8 af[16];
#pragma unroll
  for (int t = 0; t < 16; ++t) af[t] = ld8(W + (size_t)(obase + l31) * CC + t * 16 + h * 8);
  __syncthreads();
  f32x16 acc[2] = {};
#pragma unroll
  for (int t = 0; t < 16; ++t) {
    short8 b0 = ld8(&Xs[l31][t * 16 + h * 8]);
    short8 b1 = ld8(&Xs[32 + l31][t * 16 + h * 8]);
    acc[0] = __builtin_amdgcn_mfma_f32_32x32x16_bf16(af[t], b0, acc[0], 0, 0, 0);
    acc[1] = __builtin_amdgcn_mfma_f32_32x32x16_bf16(af[t], b1, acc[1], 0, 0, 0);
  }
#pragma unroll
  for (int nt = 0; nt < 2; ++nt)
#pragma unroll
    for (int reg = 0; reg < 16; ++reg) {
      int o = obase + rowmap(reg, h);
      int n = n0 + nt * 32 + l31;
      out[((size_t)b * CC + o) * NN + n] = acc[nt][reg] + ob[o];
    }
}

// ---------------------------------------------------------------------------- launch
extern "C" void kernel_launch(void* const* d_in, const int* in_sizes, int n_in,
                              void* d_out, int out_size, void* d_ws, size_t ws_size,
                              hipStream_t stream) {
  const float* xs  = (const float*)d_in[0];
  const float* xo  = (const float*)d_in[1];
  const float* qw  = (const float*)d_in[2];
  const float* qb  = (const float*)d_in[3];
  const float* kvw = (const float*)d_in[4];
  const float* kvb = (const float*)d_in[5];
  const float* g1w = (const float*)d_in[6];
  const float* g1b = (const float*)d_in[7];
  const float* g2w = (const float*)d_in[8];
  const float* g2b = (const float*)d_in[9];
  const float* dww = (const float*)d_in[10];
  const float* dwb = (const float*)d_in[11];
  const float* bng = (const float*)d_in[12];
  const float* bnb = (const float*)d_in[13];
  const float* bnm = (const float*)d_in[14];
  const float* bnv = (const float*)d_in[15];
  const float* ow  = (const float*)d_in[16];
  const float* ob  = (const float*)d_in[17];
  float* out = (float*)d_out;
  char* ws = (char*)d_ws;

  const size_t SZ  = (size_t)BB * NN * CC * 2;            // 8 MB bf16 tensor
  const size_t SZ8 = (size_t)BB * NN * CC;                // 4 MB fp8 tensor
  unsigned short* XtS    = (unsigned short*)(ws);
  unsigned short* XtO    = (unsigned short*)(ws + SZ);
  unsigned short* localT = (unsigned short*)(ws + 2 * SZ);
  unsigned char*  Qt8    = (unsigned char*)(ws + 3 * SZ);
  unsigned char*  Kt8    = (unsigned char*)(ws + 3 * SZ + SZ8);
  unsigned char*  Vv8    = (unsigned char*)(ws + 3 * SZ + 2 * SZ8);
  unsigned short* Wb     = (unsigned short*)(ws + 3 * SZ + 3 * SZ8);   // 512 KB
  float* psumA = (float*)(ws + 3 * SZ + 3 * SZ8 + 524288);             // 256 KB
  float* gate  = (float*)(ws + 3 * SZ + 3 * SZ8 + 524288 + 262144);    // 16 B
  size_t tail  = 3 * SZ + 3 * SZ8 + 524288 + 262144 + 4096;
  float* Lpart = (float*)(ws + tail);                                  // 256 KB
  unsigned short* Opart16 = (unsigned short*)(ws + tail + 262144);     // nsp*8 MB
  unsigned short* fusedT = XtS;                                        // dead after k_qkv

  size_t base = tail + 262144;
  int S = 1;
  if (ws_size >= base + 3ull * SZ) S = 3;          // 768 blocks = 3/CU
  else if (ws_size >= base + 2ull * SZ) S = 2;

  k_pre<<<dim3(4, 64, 9), 256, 0, stream>>>(xs, xo, dww, dwb, bng, bnb, bnm, bnv,
                                            qw, kvw, ow, XtS, XtO, localT, psumA, Wb);
  k_qkv<<<dim3(64, 3, 4), 256, 0, stream>>>(XtS, XtO, Wb, qb, kvb, psumA,
                                            g1w, g1b, g2w, g2b, Qt8, Kt8, Vv8, gate);
  k_flash8<<<dim3(256, S), 256, 0, stream>>>(Qt8, Kt8, Vv8, localT, gate, Opart16,
                                             Lpart, fusedT);
  k_out<<<dim3(64, 2, 4), 256, 0, stream>>>(Wb + 196608, ob, gate, localT,
                                            S > 1 ? Opart16 : nullptr, Lpart, fusedT,
                                            out, S);
}

// Round 10
// 252.782 us; speedup vs baseline: 1.2894x; 1.0054x over previous
//
#include <hip/hip_runtime.h>
#include <stdint.h>

#define BB 4
#define CC 256
#define HH 64
#define WWD 64
#define NN 4096
#define LOG2E 1.4426950408889634f

typedef __attribute__((ext_vector_type(8))) short short8;
typedef __attribute__((ext_vector_type(4))) float f32x4;
typedef __attribute__((ext_vector_type(16))) float f32x16;
typedef __attribute__((ext_vector_type(4))) unsigned short us4;
typedef unsigned long long ull;

__device__ __forceinline__ unsigned short f2bf(float f) {
  unsigned int u = __float_as_uint(f);
  u += 0x7fffu + ((u >> 16) & 1u);          // RNE
  return (unsigned short)(u >> 16);
}
__device__ __forceinline__ float bf2f(unsigned short h) {
  return __uint_as_float(((unsigned int)h) << 16);
}
__device__ __forceinline__ short8 ld8(const unsigned short* p) {
  return *reinterpret_cast<const short8*>(p);
}
__device__ __forceinline__ unsigned char f2fp8(float v) {   // OCP e4m3 via HW cvt (RNE)
  return (unsigned char)__builtin_amdgcn_cvt_pk_fp8_f32(v, v, 0, false);
}
__device__ __forceinline__ int rowmap(int reg, int h) {     // 32x32 C/D row map
  return (reg & 3) + 8 * (reg >> 2) + 4 * h;
}

// ---------------- k_pre: z<8 -> transpose (+psum, +dwconv for xs), bf16 LDS staging
//                  (34.8 KB -> 4 blocks/CU); z==8 -> weight fp32->bf16 cast slice
__global__ __launch_bounds__(256, 4) void k_pre(
    const float* __restrict__ xs, const float* __restrict__ xo,
    const float* __restrict__ dww, const float* __restrict__ dwb,
    const float* __restrict__ bng, const float* __restrict__ bnb,
    const float* __restrict__ bnm, const float* __restrict__ bnv,
    const float* __restrict__ qw, const float* __restrict__ kvw,
    const float* __restrict__ ow, unsigned short* __restrict__ XtS,
    unsigned short* __restrict__ XtO, unsigned short* __restrict__ localT,
    float* __restrict__ psumA, unsigned short* __restrict__ Wb) {
  __shared__ unsigned short rb[3][64][68];   // bf16 staging, stride 136B
  __shared__ unsigned short sb[64][68];
  int tid = threadIdx.x;
  if (blockIdx.z == 8) {                     // weight cast
    int i = (blockIdx.x * 64 + blockIdx.y) * 1024 + tid * 4;
    const float* src;
    if (i < 65536) src = qw + i;
    else if (i < 196608) src = kvw + (i - 65536);
    else src = ow + (i - 196608);
    f32x4 v = *reinterpret_cast<const f32x4*>(src);
    us4 r;
#pragma unroll
    for (int j = 0; j < 4; ++j) r[j] = f2bf(v[j]);
    *reinterpret_cast<us4*>(Wb + i) = r;
    return;
  }
  int c0 = blockIdx.x * 64, h = blockIdx.y;
  int b = blockIdx.z >> 1, which = blockIdx.z & 1;
  const float* src = which ? xo : xs;
  int wq = tid >> 6, w = tid & 63;
  int dlo = which ? 1 : 0, dhi = which ? 1 : 2;
  for (int d = dlo; d <= dhi; ++d) {
    int hh = h + d - 1;
    bool ok = (hh >= 0 && hh < HH);
#pragma unroll
    for (int p = 0; p < 4; ++p) {
      int idx = p * 256 + tid;
      int cl = idx >> 4, w4 = (idx & 15) * 4;
      f32x4 v = {};
      if (ok)
        v = *reinterpret_cast<const f32x4*>(
            &src[(((size_t)(b * CC + c0 + cl)) * HH + hh) * WWD + w4]);
      us4 rr;
#pragma unroll
      for (int j = 0; j < 4; ++j) rr[j] = f2bf(v[j]);
      *reinterpret_cast<us4*>(&rb[d][cl][w4]) = rr;
    }
  }
  __syncthreads();
  // transpose-store middle row -> Xt
  unsigned short* dst = which ? XtO : XtS;
  int n0 = h * 64, cb = (tid & 15) * 4;
#pragma unroll
  for (int i = 0; i < 4; ++i) {
    int wl = i * 16 + (tid >> 4);
    us4 r;
#pragma unroll
    for (int j = 0; j < 4; ++j) r[j] = rb[1][cb + j][wl];
    *reinterpret_cast<us4*>(&dst[((size_t)b * NN + n0 + wl) * CC + c0 + cb]) = r;
  }
  if (which) return;
  if (tid < 64) {                           // channel-sum partial (bf16-rounded inputs)
    float s = 0.f;
    for (int ww = 0; ww < 64; ++ww) s += bf2f(rb[1][tid][ww]);
    psumA[((size_t)(b * 64 + h)) * CC + c0 + tid] = s;
  }
  // depthwise 3x3 + BN + SiLU (w-edges predicated; h-halo rows pre-zeroed via ok)
  for (int p = 0; p < 16; ++p) {
    int cl = p * 4 + wq, c = c0 + cl;
    float acc = 0.f;
#pragma unroll
    for (int di = 0; di < 3; ++di)
#pragma unroll
      for (int dj = 0; dj < 3; ++dj) {
        int ww = w + dj - 1;
        float xv = (ww >= 0 && ww < 64) ? bf2f(rb[di][cl][ww]) : 0.f;
        acc = fmaf(xv, dww[c * 9 + di * 3 + dj], acc);
      }
    float y = acc + dwb[c];
    float sc = bng[c] * rsqrtf(bnv[c] + 1e-5f);
    float v = (y - bnm[c]) * sc + bnb[c];
    sb[cl][w] = f2bf(v / (1.f + __expf(-v)));
  }
  __syncthreads();
#pragma unroll
  for (int i = 0; i < 4; ++i) {
    int wl = i * 16 + (tid >> 4);
    us4 r;
#pragma unroll
    for (int j = 0; j < 4; ++j) r[j] = sb[cb + j][wl];
    *reinterpret_cast<us4*>(&localT[((size_t)b * NN + h * WWD + wl) * CC + c0 + cb]) = r;
  }
}

// --------- fused Q,K,V projections -> fp8 outputs (round-6 proven, balanced blocks);
//           + gate block (y==3). Q,K carry sqrt-split softmax scale (0.25 each).
__global__ __launch_bounds__(256, 4) void k_qkv(
    const unsigned short* __restrict__ XtS, const unsigned short* __restrict__ XtO,
    const unsigned short* __restrict__ Wb, const float* __restrict__ qb,
    const float* __restrict__ kvb, const float* __restrict__ psumA,
    const float* __restrict__ g1w, const float* __restrict__ g1b,
    const float* __restrict__ g2w, const float* __restrict__ g2b,
    unsigned char* __restrict__ Qt8, unsigned char* __restrict__ Kt8,
    unsigned char* __restrict__ Vv8, float* __restrict__ gate) {
  __shared__ unsigned short Xs[64][264];   // 33.8 KB; reused as fp8 transpose buffer
  int tid = threadIdx.x;
  int id = blockIdx.y;
  if (id == 3) {                            // gate (SE path), one working block
    if (blockIdx.x != 0 || blockIdx.z != 0) return;
    float* mf = (float*)&Xs[0][0];
    float* hpf = mf + 1024;
    int c = tid;
    for (int b4 = 0; b4 < 4; ++b4) {
      float s = 0.f;
      for (int hh = 0; hh < 64; ++hh) s += psumA[((size_t)(b4 * 64 + hh)) * CC + c];
      mf[b4 * 256 + c] = s * (1.f / 4096.f);
    }
    __syncthreads();
    for (int b4 = 0; b4 < 4; ++b4) {
      int j = tid >> 2, cq = tid & 3;
      float s = 0.f;
      for (int cc = cq * 64; cc < cq * 64 + 64; ++cc)
        s = fmaf(mf[b4 * 256 + cc], g1w[j * CC + cc], s);
      hpf[j * 5 + cq] = s;
      __syncthreads();
      if (tid < 64) {
        float hh = fmaxf(hpf[tid * 5] + hpf[tid * 5 + 1] + hpf[tid * 5 + 2] +
                             hpf[tid * 5 + 3] + g1b[tid], 0.f);
        float t = hh * g2w[tid];
        for (int off = 32; off; off >>= 1) t += __shfl_down(t, off, 64);
        if (tid == 0) gate[b4] = 1.f / (1.f + expf(-(t + g2b[0])));
      }
      __syncthreads();
    }
    return;
  }
  int n0 = blockIdx.x * 64, b = blockIdx.z;
  const unsigned short* Xt = (id == 0) ? XtS : XtO;
  const unsigned short* W = Wb + id * 65536;
  int wave = tid >> 6, lane = tid & 63, l31 = lane & 31, h = lane >> 5;
#pragma unroll
  for (int p = 0; p < 8; ++p) {
    int r = p * 8 + (tid >> 5), c = (tid & 31) * 8;
    *reinterpret_cast<uint4*>(&Xs[r][c]) =
        *reinterpret_cast<const uint4*>(Xt + ((size_t)b * NN + n0 + r) * CC + c);
  }
  __syncthreads();
  int o0 = wave * 64;
  f32x16 acc[4] = {};
  if (id < 2) {
#pragma unroll
    for (int t = 0; t < 16; ++t) {
      short8 a0 = ld8(&Xs[l31][t * 16 + h * 8]);
      short8 a1 = ld8(&Xs[32 + l31][t * 16 + h * 8]);
      short8 b0 = ld8(W + (size_t)(o0 + l31) * CC + t * 16 + h * 8);
      short8 b1 = ld8(W + (size_t)(o0 + 32 + l31) * CC + t * 16 + h * 8);
      acc[0] = __builtin_amdgcn_mfma_f32_32x32x16_bf16(a0, b0, acc[0], 0, 0, 0);
      acc[1] = __builtin_amdgcn_mfma_f32_32x32x16_bf16(a0, b1, acc[1], 0, 0, 0);
      acc[2] = __builtin_amdgcn_mfma_f32_32x32x16_bf16(a1, b0, acc[2], 0, 0, 0);
      acc[3] = __builtin_amdgcn_mfma_f32_32x32x16_bf16(a1, b1, acc[3], 0, 0, 0);
    }
    const float* bias = id ? kvb : qb;
    unsigned char* Out8 = id ? Kt8 : Qt8;
    __syncthreads();                        // Xs MFMA reads done
    unsigned char (*T8)[264] = reinterpret_cast<unsigned char(*)[264]>(&Xs[0][0]);
#pragma unroll
    for (int nt = 0; nt < 2; ++nt)
#pragma unroll
      for (int ot = 0; ot < 2; ++ot) {
        int o = o0 + ot * 32 + l31;
        float bv = bias[o];
#pragma unroll
        for (int reg = 0; reg < 16; ++reg) {
          int nl = nt * 32 + rowmap(reg, h);
          T8[nl][o] = f2fp8((acc[nt * 2 + ot][reg] + bv) * 0.25f);
        }
      }
    __syncthreads();
#pragma unroll
    for (int p = 0; p < 4; ++p) {
      int idx = p * 256 + tid, row = idx >> 4, cc = (idx & 15) * 16;
      ull a0 = *reinterpret_cast<const ull*>(&T8[row][cc]);
      ull a1 = *reinterpret_cast<const ull*>(&T8[row][cc + 8]);
      uint4 u;
      u.x = (unsigned)a0; u.y = (unsigned)(a0 >> 32);
      u.z = (unsigned)a1; u.w = (unsigned)(a1 >> 32);
      *reinterpret_cast<uint4*>(Out8 + ((size_t)b * NN + n0 + row) * CC + cc) = u;
    }
  } else {
    // V[o][n]
#pragma unroll
    for (int t = 0; t < 16; ++t) {
      short8 a0 = ld8(W + (size_t)(o0 + l31) * CC + t * 16 + h * 8);
      short8 a1 = ld8(W + (size_t)(o0 + 32 + l31) * CC + t * 16 + h * 8);
      short8 b0 = ld8(&Xs[l31][t * 16 + h * 8]);
      short8 b1 = ld8(&Xs[32 + l31][t * 16 + h * 8]);
      acc[0] = __builtin_amdgcn_mfma_f32_32x32x16_bf16(a0, b0, acc[0], 0, 0, 0);
      acc[1] = __builtin_amdgcn_mfma_f32_32x32x16_bf16(a0, b1, acc[1], 0, 0, 0);
      acc[2] = __builtin_amdgcn_mfma_f32_32x32x16_bf16(a1, b0, acc[2], 0, 0, 0);
      acc[3] = __builtin_amdgcn_mfma_f32_32x32x16_bf16(a1, b1, acc[3], 0, 0, 0);
    }
    __syncthreads();
    unsigned char (*V8)[72] = reinterpret_cast<unsigned char(*)[72]>(&Xs[0][0]);
#pragma unroll
    for (int ot = 0; ot < 2; ++ot)
#pragma unroll
      for (int nt = 0; nt < 2; ++nt)
#pragma unroll
        for (int reg = 0; reg < 16; ++reg) {
          int o = o0 + ot * 32 + rowmap(reg, h);
          int nl = nt * 32 + l31;
          V8[o][nl] = f2fp8(acc[ot * 2 + nt][reg] + kvb[CC + o]);
        }
    __syncthreads();
#pragma unroll
    for (int p = 0; p < 4; ++p) {
      int idx = p * 256 + tid, o = idx >> 2, mm = (idx & 3) * 16;
      ull a0 = *reinterpret_cast<const ull*>(&V8[o][mm]);
      ull a1 = *reinterpret_cast<const ull*>(&V8[o][mm + 8]);
      uint4 u;
      u.x = (unsigned)a0; u.y = (unsigned)(a0 >> 32);
      u.z = (unsigned)a1; u.w = (unsigned)(a1 >> 32);
      *reinterpret_cast<uint4*>(Vv8 + ((size_t)b * CC + o) * NN + n0 + mm) = u;
    }
  }
}

// ------------- flash attention, fp8 e4m3 (Q,K,V,P in LDS) — round-6/8 proven structure
__global__ __launch_bounds__(256, 3) void k_flash8(
    const unsigned char* __restrict__ Qt8, const unsigned char* __restrict__ Kt8,
    const unsigned char* __restrict__ Vv8, const unsigned short* __restrict__ localT,
    const float* __restrict__ gate, unsigned short* __restrict__ Opart16,
    float* __restrict__ Lpart, unsigned short* __restrict__ fusedT) {
  __shared__ unsigned char Ks8[64][264];
  __shared__ unsigned char Vs8[256][72];
  __shared__ unsigned char Ps8[64][72];
  __shared__ float lred[2][64];
  __shared__ float ltot[64];
  // XCD swizzle: b = x&3 -> each XCD pinned to one b; K+V fp8 = 2 MB, L2-resident
  int b = blockIdx.x & 3, n0 = (blockIdx.x >> 2) * 64;
  int sp = blockIdx.y, nsp = gridDim.y;
  int tid = threadIdx.x, wave = tid >> 6, lane = tid & 63, l31 = lane & 31, h = lane >> 5;
  int rw = wave & 1, cw = wave >> 1;
  const unsigned char* qp = Qt8 + ((size_t)b * NN + n0 + rw * 32 + l31) * CC + h * 8;
  long qf[16];
#pragma unroll
  for (int t = 0; t < 16; ++t) qf[t] = *reinterpret_cast<const long*>(qp + t * 16);
  f32x16 O[4] = {};
  float lacc[16] = {};
  int m_lo = (64 * sp) / nsp, m_hi = (64 * (sp + 1)) / nsp;
  for (int mt = m_lo; mt < m_hi; ++mt) {
    int m0 = mt * 64;
    __syncthreads();
#pragma unroll
    for (int p = 0; p < 4; ++p) {
      int idx = p * 256 + tid, m = idx >> 4, cc = (idx & 15) * 16;
      const ull* gp = reinterpret_cast<const ull*>(Kt8 + ((size_t)b * NN + m0 + m) * CC + cc);
      ull a0 = gp[0], a1 = gp[1];
      *reinterpret_cast<ull*>(&Ks8[m][cc]) = a0;
      *reinterpret_cast<ull*>(&Ks8[m][cc + 8]) = a1;
    }
#pragma unroll
    for (int p = 0; p < 4; ++p) {
      int idx = p * 256 + tid, c = idx >> 2, mm = (idx & 3) * 16;
      const ull* gp = reinterpret_cast<const ull*>(Vv8 + ((size_t)b * CC + c) * NN + m0 + mm);
      ull a0 = gp[0], a1 = gp[1];
      *reinterpret_cast<ull*>(&Vs8[c][mm]) = a0;
      *reinterpret_cast<ull*>(&Vs8[c][mm + 8]) = a1;
    }
    __syncthreads();
    f32x16 S = {};
#pragma unroll
    for (int t = 0; t < 16; ++t) {
      long kf = *reinterpret_cast<const long*>(&Ks8[cw * 32 + l31][t * 16 + h * 8]);
      S = __builtin_amdgcn_mfma_f32_32x32x16_fp8_fp8(qf[t], kf, S, 0, 0, 0);
    }
#pragma unroll
    for (int reg = 0; reg < 16; ++reg) {
      float p = __builtin_exp2f(S[reg] * LOG2E);
      lacc[reg] += p;
      Ps8[rw * 32 + rowmap(reg, h)][cw * 32 + l31] = f2fp8(p);
    }
    __syncthreads();
#pragma unroll
    for (int t = 0; t < 4; ++t) {
      long pf = *reinterpret_cast<const long*>(&Ps8[rw * 32 + l31][t * 16 + h * 8]);
#pragma unroll
      for (int ct = 0; ct < 4; ++ct) {
        long vf = *reinterpret_cast<const long*>(&Vs8[cw * 128 + ct * 32 + l31][t * 16 + h * 8]);
        O[ct] = __builtin_amdgcn_mfma_f32_32x32x16_fp8_fp8(pf, vf, O[ct], 0, 0, 0);
      }
    }
  }
#pragma unroll
  for (int reg = 0; reg < 16; ++reg) {
    float v = lacc[reg];
#pragma unroll
    for (int msk = 1; msk < 32; msk <<= 1) v += __shfl_xor(v, msk, 64);
    lacc[reg] = v;
  }
  __syncthreads();
#pragma unroll
  for (int g = 0; g < 16; ++g)
    if (l31 == g) lred[cw][rw * 32 + rowmap(g, h)] = lacc[g];
  __syncthreads();
  size_t obase2 = (size_t)(b * nsp + sp) * NN;
  if (nsp == 1) {
    if (tid < 64) ltot[tid] = lred[0][tid] + lred[1][tid];
    __syncthreads();
    float gv = gate[b];
    float inv[16];
#pragma unroll
    for (int reg = 0; reg < 16; ++reg)
      inv[reg] = gv / ltot[rw * 32 + rowmap(reg, h)];
#pragma unroll
    for (int ct = 0; ct < 4; ++ct)
#pragma unroll
      for (int reg = 0; reg < 16; ++reg) {
        int n = n0 + rw * 32 + rowmap(reg, h);
        int c = cw * 128 + ct * 32 + l31;
        size_t idx = ((size_t)b * NN + n) * CC + c;
        fusedT[idx] = f2bf(bf2f(localT[idx]) + O[ct][reg] * inv[reg]);
      }
  } else {
    if (tid < 64) Lpart[obase2 + n0 + tid] = lred[0][tid] + lred[1][tid];
#pragma unroll
    for (int ct = 0; ct < 4; ++ct)
#pragma unroll
      for (int reg = 0; reg < 16; ++reg) {
        int n = n0 + rw * 32 + rowmap(reg, h);
        int c = cw * 128 + ct * 32 + l31;
        Opart16[(obase2 + n) * CC + c] = f2bf(O[ct][reg]);
      }
  }
}

// --------- out projection with fused split-combine (Opart bf16)
__global__ __launch_bounds__(256, 4) void k_out(
    const unsigned short* __restrict__ W, const float* __restrict__ ob,
    const float* __restrict__ gate, const unsigned short* __restrict__ localT,
    const unsigned short* __restrict__ Opart16, const float* __restrict__ Lpart,
    const unsigned short* __restrict__ fusedT, float* __restrict__ out, int nsp) {
  __shared__ unsigned short Xs[64][264];
  int n0 = blockIdx.x * 64, o0 = blockIdx.y * 128, b = blockIdx.z;
  int tid = threadIdx.x, wave = tid >> 6, lane = tid & 63, l31 = lane & 31, h = lane >> 5;
  if (Opart16) {
    float gv = gate[b];
#pragma unroll
    for (int p = 0; p < 8; ++p) {
      int r = p * 8 + (tid >> 5), cc = (tid & 31) * 8;
      int n = n0 + r;
      float lsum = 0.f;
      for (int sp = 0; sp < nsp; ++sp) lsum += Lpart[(size_t)(b * nsp + sp) * NN + n];
      float g = gv / lsum;
      float ov[8] = {};
      for (int sp = 0; sp < nsp; ++sp) {
        short8 x = ld8(Opart16 + ((size_t)(b * nsp + sp) * NN + n) * CC + cc);
#pragma unroll
        for (int j = 0; j < 8; ++j) ov[j] += bf2f(((unsigned short*)&x)[j]);
      }
      const unsigned short* lp = localT + ((size_t)b * NN + n) * CC + cc;
      short8 lv = ld8(lp);
      us4 r0, r1;
#pragma unroll
      for (int j = 0; j < 4; ++j) {
        r0[j] = f2bf(bf2f(((unsigned short*)&lv)[j]) + ov[j] * g);
        r1[j] = f2bf(bf2f(((unsigned short*)&lv)[j + 4]) + ov[j + 4] * g);
      }
      *reinterpret_cast<us4*>(&Xs[r][cc]) = r0;
      *reinterpret_cast<us4*>(&Xs[r][cc + 4]) = r1;
    }
  } else {
#pragma unroll
    for (int p = 0; p < 8; ++p) {
      int r = p * 8 + (tid >> 5), c = (tid & 31) * 8;
      *reinterpret_cast<uint4*>(&Xs[r][c]) =
          *reinterpret_cast<const uint4*>(fusedT + ((size_t)b * NN + n0 + r) * CC + c);
    }
  }
  int obase = o0 + wave * 32;
  short8 af[16];
#pragma unroll
  for (int t = 0; t < 16; ++t) af[t] = ld8(W + (size_t)(obase + l31) * CC + t * 16 + h * 8);
  __syncthreads();
  f32x16 acc[2] = {};
#pragma unroll
  for (int t = 0; t < 16; ++t) {
    short8 b0 = ld8(&Xs[l31][t * 16 + h * 8]);
    short8 b1 = ld8(&Xs[32 + l31][t * 16 + h * 8]);
    acc[0] = __builtin_amdgcn_mfma_f32_32x32x16_bf16(af[t], b0, acc[0], 0, 0, 0);
    acc[1] = __builtin_amdgcn_mfma_f32_32x32x16_bf16(af[t], b1, acc[1], 0, 0, 0);
  }
#pragma unroll
  for (int nt = 0; nt < 2; ++nt)
#pragma unroll
    for (int reg = 0; reg < 16; ++reg) {
      int o = obase + rowmap(reg, h);
      int n = n0 + nt * 32 + l31;
      out[((size_t)b * CC + o) * NN + n] = acc[nt][reg] + ob[o];
    }
}

// ---------------------------------------------------------------------------- launch
extern "C" void kernel_launch(void* const* d_in, const int* in_sizes, int n_in,
                              void* d_out, int out_size, void* d_ws, size_t ws_size,
                              hipStream_t stream) {
  const float* xs  = (const float*)d_in[0];
  const float* xo  = (const float*)d_in[1];
  const float* qw  = (const float*)d_in[2];
  const float* qb  = (const float*)d_in[3];
  const float* kvw = (const float*)d_in[4];
  const float* kvb = (const float*)d_in[5];
  const float* g1w = (const float*)d_in[6];
  const float* g1b = (const float*)d_in[7];
  const float* g2w = (const float*)d_in[8];
  const float* g2b = (const float*)d_in[9];
  const float* dww = (const float*)d_in[10];
  const float* dwb = (const float*)d_in[11];
  const float* bng = (const float*)d_in[12];
  const float* bnb = (const float*)d_in[13];
  const float* bnm = (const float*)d_in[14];
  const float* bnv = (const float*)d_in[15];
  const float* ow  = (const float*)d_in[16];
  const float* ob  = (const float*)d_in[17];
  float* out = (float*)d_out;
  char* ws = (char*)d_ws;

  const size_t SZ  = (size_t)BB * NN * CC * 2;            // 8 MB bf16 tensor
  const size_t SZ8 = (size_t)BB * NN * CC;                // 4 MB fp8 tensor
  unsigned short* XtS    = (unsigned short*)(ws);
  unsigned short* XtO    = (unsigned short*)(ws + SZ);
  unsigned short* localT = (unsigned short*)(ws + 2 * SZ);
  unsigned char*  Qt8    = (unsigned char*)(ws + 3 * SZ);
  unsigned char*  Kt8    = (unsigned char*)(ws + 3 * SZ + SZ8);
  unsigned char*  Vv8    = (unsigned char*)(ws + 3 * SZ + 2 * SZ8);
  unsigned short* Wb     = (unsigned short*)(ws + 3 * SZ + 3 * SZ8);   // 512 KB
  float* psumA = (float*)(ws + 3 * SZ + 3 * SZ8 + 524288);             // 256 KB
  float* gate  = (float*)(ws + 3 * SZ + 3 * SZ8 + 524288 + 262144);    // 16 B
  size_t tail  = 3 * SZ + 3 * SZ8 + 524288 + 262144 + 4096;
  float* Lpart = (float*)(ws + tail);                                  // 256 KB
  unsigned short* Opart16 = (unsigned short*)(ws + tail + 262144);     // nsp*8 MB
  unsigned short* fusedT = XtS;                                        // dead after k_qkv

  size_t base = tail + 262144;
  int S = 1;
  if (ws_size >= base + 3ull * SZ) S = 3;          // 768 blocks = 3/CU
  else if (ws_size >= base + 2ull * SZ) S = 2;

  k_pre<<<dim3(4, 64, 9), 256, 0, stream>>>(xs, xo, dww, dwb, bng, bnb, bnm, bnv,
                                            qw, kvw, ow, XtS, XtO, localT, psumA, Wb);
  k_qkv<<<dim3(64, 4, 4), 256, 0, stream>>>(XtS, XtO, Wb, qb, kvb, psumA,
                                            g1w, g1b, g2w, g2b, Qt8, Kt8, Vv8, gate);
  k_flash8<<<dim3(256, S), 256, 0, stream>>>(Qt8, Kt8, Vv8, localT, gate, Opart16,
                                             Lpart, fusedT);
  k_out<<<dim3(64, 2, 4), 256, 0, stream>>>(Wb + 196608, ob, gate, localT,
                                            S > 1 ? Opart16 : nullptr, Lpart, fusedT,
                                            out, S);
}